// Round 7
// baseline (709.276 us; speedup 1.0000x reference)
//
#include <hip/hip_runtime.h>

typedef short short8 __attribute__((ext_vector_type(8)));
typedef short short4v __attribute__((ext_vector_type(4)));
typedef float floatx4 __attribute__((ext_vector_type(4)));

#define D_MODEL 1024
#define N_HEADS 16
#define HEAD    64
#define D_FF    4096
#define SEQ     2048
#define BATCH   4
#define TOKENS  (BATCH*SEQ)   // 8192

__device__ __forceinline__ float b2f(unsigned short u) {
  return __uint_as_float(((unsigned)u) << 16);
}
__device__ __forceinline__ unsigned short f2b(float f) {
  unsigned u = __float_as_uint(f);
  unsigned r = 0x7fffu + ((u >> 16) & 1u);
  return (unsigned short)((u + r) >> 16);
}
__device__ __forceinline__ floatx4 mfma16(short8 a, short8 b, floatx4 c) {
  return __builtin_amdgcn_mfma_f32_16x16x32_bf16(a, b, c, 0, 0, 0);
}
__device__ __forceinline__ void load16_lds(const unsigned short* g, unsigned short* l) {
  __builtin_amdgcn_global_load_lds((const __attribute__((address_space(1))) void*)g,
                                   (__attribute__((address_space(3))) void*)l, 16, 0, 0);
}

// ---------------- fused prep: x->bf16, QKV repack, Wo/W1/W2 transpose ----------------
__device__ __forceinline__ void transp_body(
    const float* __restrict__ src, unsigned short* __restrict__ dst,
    int R, int C, int bx, int by, float (*t)[65])
{
  int cb = bx * 64, rb = by * 64;
#pragma unroll
  for (int i = 0; i < 16; i++) {
    int idx = i * 256 + threadIdx.x;
    int lr = idx >> 6, lc = idx & 63;
    t[lr][lc] = src[(size_t)(rb + lr) * C + cb + lc];
  }
  __syncthreads();
#pragma unroll
  for (int i = 0; i < 16; i++) {
    int idx = i * 256 + threadIdx.x;
    int lc = idx >> 6, lr = idx & 63;
    dst[(size_t)(cb + lc) * R + rb + lr] = f2b(t[lr][lc]);
  }
}

__global__ __launch_bounds__(256) void prep_kernel(
    const float* __restrict__ x, unsigned short* __restrict__ x_bf,
    const float* __restrict__ Wq, const float* __restrict__ Wk,
    const float* __restrict__ Wv, unsigned short* __restrict__ qkv_bt,
    const float* __restrict__ Wo, unsigned short* __restrict__ wo_bt,
    const float* __restrict__ W1, unsigned short* __restrict__ w1_bt,
    const float* __restrict__ W2, unsigned short* __restrict__ w2_bt)
{
  __shared__ float t[64][65];
  int bid = blockIdx.x;
  if (bid < 8192) {                       // x fp32 -> bf16
    int idx = bid * 1024 + threadIdx.x * 4;
    float4 v = *(const float4*)(x + idx);
    short4v o;
    o[0] = (short)f2b(v.x); o[1] = (short)f2b(v.y);
    o[2] = (short)f2b(v.z); o[3] = (short)f2b(v.w);
    *(short4v*)(x_bf + idx) = o;
  } else if (bid < 8960) {                // QKV repack: W[h][d][e] -> [c][d]
    int by = bid - 8192;
    int xt = by & 15, z = by >> 4;
    int sel = z >> 4, h = z & 15;
    const float* W = (sel == 0) ? Wq : ((sel == 1) ? Wk : Wv);
    const float* src = W + (size_t)h * D_MODEL * HEAD;
    int rb = xt * 64;
#pragma unroll
    for (int i = 0; i < 16; i++) {
      int idx = i * 256 + threadIdx.x;
      int lr = idx >> 6, lc = idx & 63;
      t[lr][lc] = src[(size_t)(rb + lr) * HEAD + lc];
    }
    __syncthreads();
    unsigned short* d0 = qkv_bt + (size_t)(sel * 1024 + h * 64) * D_MODEL;
#pragma unroll
    for (int i = 0; i < 16; i++) {
      int idx = i * 256 + threadIdx.x;
      int lc = idx >> 6, lr = idx & 63;
      d0[(size_t)lc * D_MODEL + rb + lr] = f2b(t[lr][lc]);
    }
  } else if (bid < 9216) {                // Wo^T
    int i = bid - 8960;
    transp_body(Wo, wo_bt, 1024, 1024, i & 15, i >> 4, t);
  } else if (bid < 10240) {               // W1^T
    int i = bid - 9216;
    transp_body(W1, w1_bt, 1024, 4096, i & 63, i >> 6, t);
  } else {                                // W2^T
    int i = bid - 10240;
    transp_body(W2, w2_bt, 4096, 1024, i & 15, i >> 4, t);
  }
}

// ---------------- 256x256x64 bf16 GEMM, 8-wave 4-phase counted-vmcnt pipeline ------
// Single vmcnt(4) per K-tile at phase 4. Ledger: at tile t ph4, outstanding =
// A1(t+1),B1(t+1),A0(t+2),B0(t+2) = 8 loads; vmcnt(4) retires A1(t+1),B1(t+1)
// and everything older -> all of tile t+1 landed before tile t+1 ph1 reads it.
// WAR: STG into a region is issued >=1 full phase after that region's readers
// drained (lgkmcnt(0) before the MFMA of the reading phase).
// epi 0 = QKV split write (q pre-scaled by log2e/32 for exp2 softmax), epi 2 = relu bf16.
__global__ __launch_bounds__(512, 2) void gemm256(
    const unsigned short* __restrict__ A, const unsigned short* __restrict__ BT,
    const float* __restrict__ biasf, void* __restrict__ outp,
    int M, int N, int K, int epi)
{
  __shared__ unsigned short a_sh[2 * 256 * 64];   // [buf][row][64]
  __shared__ unsigned short b_sh[2 * 256 * 64];   // [buf][permrow][64]

  const int tid  = threadIdx.x;
  const int lane = tid & 63;
  const int wave = tid >> 6;        // 0..7
  const int quad = lane >> 4;
  const int l15  = lane & 15;
  const int wm   = wave >> 2;       // 0..1
  const int wn   = wave & 3;        // 0..3

  // XCD swizzle: M/256 = 32 row-tiles, 4 per XCD (contiguous A band per XCD L2)
  const int lin = blockIdx.y * gridDim.x + blockIdx.x;
  const int xcd = lin & 7, j = lin >> 3;
  const int m0 = (xcd * 4 + (j & 3)) * 256;
  const int n0 = (j >> 2) * 256;

  // staging: thread covers (row u, chunk tid&7) of each 64-row call;
  // source chunk pre-swizzled so LDS content at (r,cc) = logical chunk cc^(r&7)
  const int u  = tid >> 3;                       // 0..63
  const int sc = (tid & 7) ^ (u & 7);
  const unsigned short* a_src = A  + (size_t)(m0 + u) * K + sc * 8;
  const int borig = ((u >> 5) * 64) + (u & 31);  // perm-row -> orig BT row (base)
  const unsigned short* b_src = BT + (size_t)(n0 + borig) * K + sc * 8;
  unsigned short* a_dst = a_sh + wave * 512;     // + buf*16384 + Rc*64
  unsigned short* b_dst = b_sh + wave * 512;

#define SA(T, Rc)  load16_lds(a_src + (size_t)(Rc) * K + (T) * 64, \
                              a_dst + ((T) & 1) * 16384 + (Rc) * 64)
#define SB(T, Rb, Radd) load16_lds(b_src + (size_t)(Radd) * K + (T) * 64, \
                              b_dst + ((T) & 1) * 16384 + (Rb) * 64)
#define STG_A0(T) do { SA(T, 0);   SA(T, 128); } while (0)          // qm=0 rows
#define STG_A1(T) do { SA(T, 64);  SA(T, 192); } while (0)          // qm=1 rows
#define STG_B0(T) do { SB(T, 0, 0);    SB(T, 64, 128); } while (0)  // qn=0 rows
#define STG_B1(T) do { SB(T, 128, 32); SB(T, 192, 160); } while (0) // qn=1 rows

  floatx4 acc[8][4] = {};
  short8 aF[4][2];        // current qm sub-band, both k-halves
  short8 bF[2][2][2];     // [qn][ni][kh] - both qn sets held across the tile
  const unsigned short* ash = a_sh;
  const unsigned short* bsh = b_sh;

#define LDA(QM) \
  _Pragma("unroll") for (int mi = 0; mi < 4; mi++) \
  _Pragma("unroll") for (int kh = 0; kh < 2; kh++) \
    aF[mi][kh] = *(const short8*)(ash + (wm * 128 + (QM) * 64 + mi * 16 + l15) * 64 \
                                  + (((kh * 4 + quad) ^ (l15 & 7)) * 8));
#define LDB(QN) \
  _Pragma("unroll") for (int ni = 0; ni < 2; ni++) \
  _Pragma("unroll") for (int kh = 0; kh < 2; kh++) \
    bF[QN][ni][kh] = *(const short8*)(bsh + ((QN) * 128 + wn * 32 + ni * 16 + l15) * 64 \
                                      + (((kh * 4 + quad) ^ (l15 & 7)) * 8));
#define MM(QM, QN) \
  _Pragma("unroll") for (int mi = 0; mi < 4; mi++) \
  _Pragma("unroll") for (int ni = 0; ni < 2; ni++) { \
    acc[(QM) * 4 + mi][(QN) * 2 + ni] = \
        mfma16(aF[mi][0], bF[QN][ni][0], acc[(QM) * 4 + mi][(QN) * 2 + ni]); \
    acc[(QM) * 4 + mi][(QN) * 2 + ni] = \
        mfma16(aF[mi][1], bF[QN][ni][1], acc[(QM) * 4 + mi][(QN) * 2 + ni]); \
  }
#define PH_VM(N) asm volatile("s_waitcnt vmcnt(" #N ")" ::: "memory");
#define PH_MID() \
  __builtin_amdgcn_s_barrier(); \
  asm volatile("s_waitcnt lgkmcnt(0)" ::: "memory"); \
  __builtin_amdgcn_sched_barrier(0); \
  __builtin_amdgcn_s_setprio(1);
#define PH_END() \
  __builtin_amdgcn_s_setprio(0); \
  __builtin_amdgcn_s_barrier();

  const int NT = K >> 6;

  // prologue: tile0 fully + tile1 first-needed halves
  STG_A0(0); STG_B0(0); STG_A1(0); STG_B1(0); STG_A0(1); STG_B0(1);
  PH_VM(4)                                           // retire all of tile 0
  __builtin_amdgcn_s_barrier();

  for (int t = 0; t < NT - 2; ++t) {
    ash = a_sh + (t & 1) * 16384;
    bsh = b_sh + (t & 1) * 16384;

    LDA(0) LDB(0)
    STG_A1(t + 1);
    PH_MID() MM(0, 0) PH_END();

    LDB(1)
    STG_B1(t + 1);
    PH_MID() MM(0, 1) PH_END();

    LDA(1)
    STG_A0(t + 2);
    PH_MID() MM(1, 0) PH_END();

    STG_B0(t + 2);
    PH_VM(4)
    PH_MID() MM(1, 1) PH_END();
  }
  {// tile NT-2: no t+2 staging; drain toward tail
    const int t = NT - 2;
    ash = a_sh + (t & 1) * 16384;
    bsh = b_sh + (t & 1) * 16384;

    LDA(0) LDB(0)
    STG_A1(t + 1);
    PH_MID() MM(0, 0) PH_END();

    LDB(1)
    STG_B1(t + 1);
    PH_MID() MM(0, 1) PH_END();

    LDA(1)
    PH_MID() MM(1, 0) PH_END();

    PH_VM(0)
    PH_MID() MM(1, 1) PH_END();
  }
  {// tile NT-1: final tile, no staging, no waits needed
    const int t = NT - 1;
    ash = a_sh + (t & 1) * 16384;
    bsh = b_sh + (t & 1) * 16384;

    LDA(0) LDB(0)
    PH_MID() MM(0, 0) PH_END();

    LDB(1)
    PH_MID() MM(0, 1) PH_END();

    LDA(1)
    PH_MID() MM(1, 0) PH_END();

    PH_MID() MM(1, 1) PH_END();
  }

#undef SA
#undef SB
#undef STG_A0
#undef STG_A1
#undef STG_B0
#undef STG_B1
#undef LDA
#undef LDB
#undef MM
#undef PH_VM
#undef PH_MID
#undef PH_END

#pragma unroll
  for (int mi = 0; mi < 8; mi++) {
#pragma unroll
    for (int ni = 0; ni < 4; ni++) {
      const int col = n0 + wn * 64 + ni * 16 + l15;
      const int row0 = m0 + wm * 128 + mi * 16 + quad * 4;
      if (epi == 0) {
        int sel = col >> 10;
        int cc = col & 1023;
        int h = cc >> 6, e = cc & 63;
        int b = row0 >> 11, s0 = row0 & 2047;
        if (sel < 2) {
          unsigned short* base = (unsigned short*)outp + (size_t)sel * 8388608;
#pragma unroll
          for (int r = 0; r < 4; r++) {
            // q scaled by log2e/sqrt(D_MODEL) so attn can use native exp2
            float v2 = (sel == 0) ? acc[mi][ni][r] * 0.04508422f : acc[mi][ni][r];
            base[((size_t)((b * N_HEADS + h) * SEQ + (s0 + r))) * HEAD + e] = f2b(v2);
          }
        } else {
          unsigned short* base = (unsigned short*)outp + (size_t)2 * 8388608;
          short4v pk;
#pragma unroll
          for (int r = 0; r < 4; r++) pk[r] = (short)f2b(acc[mi][ni][r]);
          *(short4v*)(base + ((size_t)((b * N_HEADS + h) * HEAD + e)) * SEQ + s0) = pk;
        }
      } else {  // epi 2: relu -> bf16
#pragma unroll
        for (int r = 0; r < 4; r++)
          ((unsigned short*)outp)[(size_t)(row0 + r) * N + col] =
              f2b(fmaxf(acc[mi][ni][r] + biasf[col], 0.0f));
      }
    }
  }
}

// ---------------- 256x128x64 bf16 GEMM, 8-wave 2-phase counted-vmcnt pipeline ------
// For the N=1024 GEMMs (Wo, W2): grid 32x8 = 256 blocks = 1/CU, 512 thr = 8 waves
// (4M x 2N, 64x64 per wave). LDS 96 KiB: A 2x[256][64], B 2x[128][64], chunk-XOR
// swizzled (content at (r,cc) = logical chunk cc^(r&7), staged via pre-swizzled src).
// 2 phases/K-tile, 16 MFMA each; counted vmcnt(4) once per tile.
// epi 1: fp32 out = acc + biasf[col] + residf[row*N+col]
// epi 3: fp32 out = acc + biasf[col] + b2f(residb[row*N+col])
__global__ __launch_bounds__(512, 2) void gemm256n(
    const unsigned short* __restrict__ A, const unsigned short* __restrict__ BT,
    const float* __restrict__ biasf, const float* __restrict__ residf,
    const unsigned short* __restrict__ residb, void* __restrict__ outp,
    int M, int N, int K, int epi)
{
  __shared__ unsigned short a_sh[2 * 256 * 64];   // 64 KiB
  __shared__ unsigned short b_sh[2 * 128 * 64];   // 32 KiB

  const int tid  = threadIdx.x;
  const int lane = tid & 63;
  const int wave = tid >> 6;        // 0..7
  const int quad = lane >> 4;
  const int l15  = lane & 15;
  const int wm   = wave >> 1;       // 0..3
  const int wn   = wave & 1;        // 0..1

  // XCD swizzle: 32 row-tiles, 4 per XCD; 8 col-tiles
  const int lin = blockIdx.y * gridDim.x + blockIdx.x;
  const int xcd = lin & 7, j = lin >> 3;
  const int m0 = (xcd * 4 + (j & 3)) * 256;
  const int n0 = (j >> 2) * 128;

  const int u  = tid >> 3;                       // 0..63
  const int sc = (tid & 7) ^ (u & 7);
  const unsigned short* a_src = A  + (size_t)(m0 + u) * K + sc * 8;
  const unsigned short* b_src = BT + (size_t)(n0 + u) * K + sc * 8;
  unsigned short* a_dst = a_sh + wave * 512;
  unsigned short* b_dst = b_sh + wave * 512;

#define SA(T, Rc) load16_lds(a_src + (size_t)(Rc) * K + (T) * 64, \
                             a_dst + ((T) & 1) * 16384 + (Rc) * 64)
#define SB(T, Rb) load16_lds(b_src + (size_t)(Rb) * K + (T) * 64, \
                             b_dst + ((T) & 1) * 8192 + (Rb) * 64)
#define STG_A0(T) do { SA(T, 0);   SA(T, 64);  } while (0)   // rows 0..127
#define STG_A1(T) do { SA(T, 128); SA(T, 192); } while (0)   // rows 128..255
#define STG_B(T)  do { SB(T, 0);   SB(T, 64);  } while (0)   // all 128 B rows

  floatx4 acc[4][4] = {};
  short8 aF[2][2];        // current QM: [mi][kh]
  short8 bF[2][2][2];     // [QN][ni][kh] - held across the tile
  const unsigned short* ash = a_sh;
  const unsigned short* bsh = b_sh;

#define LDA(QM) \
  _Pragma("unroll") for (int mi = 0; mi < 2; mi++) \
  _Pragma("unroll") for (int kh = 0; kh < 2; kh++) \
    aF[mi][kh] = *(const short8*)(ash + ((QM) * 128 + wm * 32 + mi * 16 + l15) * 64 \
                                  + (((kh * 4 + quad) ^ (l15 & 7)) * 8));
#define LDB(QN) \
  _Pragma("unroll") for (int ni = 0; ni < 2; ni++) \
  _Pragma("unroll") for (int kh = 0; kh < 2; kh++) \
    bF[QN][ni][kh] = *(const short8*)(bsh + ((QN) * 64 + wn * 32 + ni * 16 + l15) * 64 \
                                      + (((kh * 4 + quad) ^ (l15 & 7)) * 8));
#define MM2(QM) \
  _Pragma("unroll") for (int qn = 0; qn < 2; qn++) \
  _Pragma("unroll") for (int mi = 0; mi < 2; mi++) \
  _Pragma("unroll") for (int ni = 0; ni < 2; ni++) { \
    acc[(QM) * 2 + mi][qn * 2 + ni] = \
        mfma16(aF[mi][0], bF[qn][ni][0], acc[(QM) * 2 + mi][qn * 2 + ni]); \
    acc[(QM) * 2 + mi][qn * 2 + ni] = \
        mfma16(aF[mi][1], bF[qn][ni][1], acc[(QM) * 2 + mi][qn * 2 + ni]); \
  }
#define PH_VM(N) asm volatile("s_waitcnt vmcnt(" #N ")" ::: "memory");
#define PH_MID() \
  __builtin_amdgcn_s_barrier(); \
  asm volatile("s_waitcnt lgkmcnt(0)" ::: "memory"); \
  __builtin_amdgcn_sched_barrier(0); \
  __builtin_amdgcn_s_setprio(1);
#define PH_END() \
  __builtin_amdgcn_s_setprio(0); \
  __builtin_amdgcn_s_barrier();

  const int NT = K >> 6;

  // prologue: tile0 fully + tile1 ph1-needed regions
  STG_A0(0); STG_B(0); STG_A1(0); STG_A0(1); STG_B(1);
  PH_VM(4)                            // retire all 6 of tile 0; keep A0(1),B(1)
  __builtin_amdgcn_s_barrier();

  for (int t = 0; t < NT - 2; ++t) {
    ash = a_sh + (t & 1) * 16384;
    bsh = b_sh + (t & 1) * 8192;

    LDA(0) LDB(0) LDB(1)
    STG_A1(t + 1);
    PH_MID() MM2(0) PH_END();

    LDA(1)
    STG_A0(t + 2); STG_B(t + 2);
    PH_VM(4)
    PH_MID() MM2(1) PH_END();
  }
  {// tile NT-2: stage only A1(NT-1); drain
    const int t = NT - 2;
    ash = a_sh + (t & 1) * 16384;
    bsh = b_sh + (t & 1) * 8192;

    LDA(0) LDB(0) LDB(1)
    STG_A1(t + 1);
    PH_MID() MM2(0) PH_END();

    LDA(1)
    PH_VM(0)
    PH_MID() MM2(1) PH_END();
  }
  {// tile NT-1: no staging
    const int t = NT - 1;
    ash = a_sh + (t & 1) * 16384;
    bsh = b_sh + (t & 1) * 8192;

    LDA(0) LDB(0) LDB(1)
    PH_MID() MM2(0) PH_END();

    LDA(1)
    PH_MID() MM2(1) PH_END();
  }

#undef SA
#undef SB
#undef STG_A0
#undef STG_A1
#undef STG_B
#undef LDA
#undef LDB
#undef MM2
#undef PH_VM
#undef PH_MID
#undef PH_END

#pragma unroll
  for (int am = 0; am < 4; am++) {
    const int row0 = m0 + (am >> 1) * 128 + wm * 32 + (am & 1) * 16 + quad * 4;
#pragma unroll
    for (int bn = 0; bn < 4; bn++) {
      const int col = n0 + (bn >> 1) * 64 + wn * 32 + (bn & 1) * 16 + l15;
      if (epi == 1) {
#pragma unroll
        for (int r = 0; r < 4; r++)
          ((float*)outp)[(size_t)(row0 + r) * N + col] =
              acc[am][bn][r] + biasf[col] + residf[(size_t)(row0 + r) * N + col];
      } else {
#pragma unroll
        for (int r = 0; r < 4; r++)
          ((float*)outp)[(size_t)(row0 + r) * N + col] =
              acc[am][bn][r] + biasf[col] + b2f(residb[(size_t)(row0 + r) * N + col]);
      }
    }
  }
}

// ---------------- flash attention v3: S^T, exp2 + MFMA row-sum, NO K/V staging ------
// attn is latency-bound and lives on TLP (R5: LDS dbuf cost a resident block,
// -44%). K and V fragments are IDENTICAL across the 4 waves, so per-CU L1 dedupes
// redundant wave reads -- no K/V LDS staging, fragments read straight from global
// (16 rows x 64B aligned segments per load instruction). No __syncthreads at all
// (p_sh is wave-private; write->read ordering is per-wave lgkmcnt). LDS 18 KB ->
// 6 blocks/CU (launch_bounds(256,6)). bh-clustered XCD swizzle: the 16 qt-blocks
// of one bh sit on one XCD -> concurrent blocks stream the same K/V through L1/L2.
__global__ __launch_bounds__(256, 6) void attn_kernel(
    const unsigned short* __restrict__ q, const unsigned short* __restrict__ k,
    const unsigned short* __restrict__ vt, unsigned short* __restrict__ o)
{
  // bijective bh-clustering swizzle: lin = g*8 + xcd; qt = g&15; bh = (g>>4)*8 + xcd
  const int lin = blockIdx.y * gridDim.x + blockIdx.x;   // gridDim.x = 16
  const int xcd = lin & 7, g = lin >> 3;
  const int qt = g & 15;
  const int bh = (g >> 4) * 8 + xcd;

  const int tid = threadIdx.x, lane = tid & 63, wave = tid >> 6;
  const int quad = lane >> 4, l15 = lane & 15;
  const size_t base = (size_t)bh * SEQ * HEAD;

  __shared__ unsigned short p_sh[4 * 32 * 72];
  unsigned short* pw = p_sh + wave * 32 * 72;  // wave-private P [m 32][t 64+pad]

  short8 qf[2][2];
#pragma unroll
  for (int mj = 0; mj < 2; mj++) {
    const unsigned short* qp =
        q + base + (size_t)(qt * 128 + wave * 32 + mj * 16 + l15) * HEAD;
    qf[mj][0] = *(const short8*)(qp + quad * 8);
    qf[mj][1] = *(const short8*)(qp + 32 + quad * 8);
  }

  floatx4 oacc[2][4] = {};
  floatx4 rsacc[2] = {};   // row sums live in col 0 (lanes with l15==0)

  // ones B-fragment: B[row 0][k] = 1.0bf16, rows 1..15 = 0
  short8 onesf;
  {
    short ov = (l15 == 0) ? (short)0x3F80 : (short)0;
#pragma unroll
    for (int jj = 0; jj < 8; jj++) onesf[jj] = ov;
  }

  for (int kt = 0; kt < SEQ / 64; kt++) {
    const unsigned short* kb = k + base + (size_t)kt * 64 * HEAD;
    const unsigned short* vb = vt + base + (size_t)kt * 64;

    // S^T tile: A = K rows (t) straight from global, B = Q rows (m)
#pragma unroll
    for (int ti = 0; ti < 4; ti++) {
      int t = ti * 16 + l15;
      short8 kf0 = *(const short8*)(kb + (size_t)t * HEAD + quad * 8);
      short8 kf1 = *(const short8*)(kb + (size_t)t * HEAD + 32 + quad * 8);
      floatx4 s0 = {0.f, 0.f, 0.f, 0.f}, s1 = {0.f, 0.f, 0.f, 0.f};
      __builtin_amdgcn_s_setprio(1);
      s0 = mfma16(kf0, qf[0][0], s0);
      s0 = mfma16(kf1, qf[0][1], s0);
      s1 = mfma16(kf0, qf[1][0], s1);
      s1 = mfma16(kf1, qf[1][1], s1);
      __builtin_amdgcn_s_setprio(0);
#pragma unroll
      for (int mj = 0; mj < 2; mj++) {
        floatx4 s = mj ? s1 : s0;
        float p0 = __builtin_amdgcn_exp2f(s[0]);
        float p1 = __builtin_amdgcn_exp2f(s[1]);
        float p2 = __builtin_amdgcn_exp2f(s[2]);
        float p3 = __builtin_amdgcn_exp2f(s[3]);
        uint2 u;
        u.x = __builtin_amdgcn_perm(__float_as_uint(p1), __float_as_uint(p0), 0x07060302u);
        u.y = __builtin_amdgcn_perm(__float_as_uint(p3), __float_as_uint(p2), 0x07060302u);
        *(uint2*)(pw + (mj * 16 + l15) * 72 + ti * 16 + quad * 4) = u;
      }
    }

    // O += P @ V   (A = P[m][t], B = V^T[e][t] straight from global); rs += P @ 1
    {
      short8 pf[2][2];
#pragma unroll
      for (int mj = 0; mj < 2; mj++) {
        pf[mj][0] = *(const short8*)(pw + (mj * 16 + l15) * 72 + quad * 8);
        pf[mj][1] = *(const short8*)(pw + (mj * 16 + l15) * 72 + 32 + quad * 8);
      }
      __builtin_amdgcn_s_setprio(1);
#pragma unroll
      for (int ni = 0; ni < 4; ni++) {
        int e = ni * 16 + l15;
        short8 bv0 = *(const short8*)(vb + (size_t)e * SEQ + quad * 8);
        short8 bv1 = *(const short8*)(vb + (size_t)e * SEQ + 32 + quad * 8);
#pragma unroll
        for (int mj = 0; mj < 2; mj++) {
          oacc[mj][ni] = mfma16(pf[mj][0], bv0, oacc[mj][ni]);
          oacc[mj][ni] = mfma16(pf[mj][1], bv1, oacc[mj][ni]);
        }
      }
#pragma unroll
      for (int mj = 0; mj < 2; mj++) {
        rsacc[mj] = mfma16(pf[mj][0], onesf, rsacc[mj]);
        rsacc[mj] = mfma16(pf[mj][1], onesf, rsacc[mj]);
      }
      __builtin_amdgcn_s_setprio(0);
    }
  }

  const int b = bh >> 4, h = bh & 15;
#pragma unroll
  for (int mj = 0; mj < 2; mj++)
#pragma unroll
    for (int r = 0; r < 4; r++) {
      int s = qt * 128 + wave * 32 + mj * 16 + quad * 4 + r;
      // rs for row m=quad*4+r sits in lane quad*16 (l15==0), element r
      float rsv = __shfl(rsacc[mj][r], quad * 16, 64);
      float inv = 1.0f / rsv;
#pragma unroll
      for (int ni = 0; ni < 4; ni++)
        o[((size_t)(b * SEQ + s)) * D_MODEL + h * HEAD + ni * 16 + l15] =
            f2b(oacc[mj][ni][r] * inv);
    }
}

// ---------------- layernorm: wave-per-row, no LDS/barrier ----------------
__global__ __launch_bounds__(256) void ln_kernel(
    const float* __restrict__ in, const float* __restrict__ g,
    const float* __restrict__ be, void* __restrict__ outp, int write_bf16)
{
  const int row = blockIdx.x * 4 + (threadIdx.x >> 6);
  const int lane = threadIdx.x & 63;
  const float* xp = in + (size_t)row * D_MODEL;
  float4 xv[4];
  float s = 0.0f, ss = 0.0f;
#pragma unroll
  for (int j = 0; j < 4; j++) {
    xv[j] = *(const float4*)(xp + j * 256 + lane * 4);
    s += (xv[j].x + xv[j].y) + (xv[j].z + xv[j].w);
    ss += (xv[j].x * xv[j].x + xv[j].y * xv[j].y) +
          (xv[j].z * xv[j].z + xv[j].w * xv[j].w);
  }
#pragma unroll
  for (int m = 1; m < 64; m <<= 1) {
    s += __shfl_xor(s, m, 64);
    ss += __shfl_xor(ss, m, 64);
  }
  float mean = s * (1.0f / 1024.0f);
  float var = fmaxf((ss - 1024.0f * mean * mean) * (1.0f / 1023.0f), 0.0f);
  float inv = 1.0f / (sqrtf(var) + 1e-6f);
#pragma unroll
  for (int j = 0; j < 4; j++) {
    int c = j * 256 + lane * 4;
    float4 g4 = *(const float4*)(g + c);
    float4 b4 = *(const float4*)(be + c);
    float y0 = g4.x * ((xv[j].x + mean) * inv) + b4.x;
    float y1 = g4.y * ((xv[j].y + mean) * inv) + b4.y;
    float y2 = g4.z * ((xv[j].z + mean) * inv) + b4.z;
    float y3 = g4.w * ((xv[j].w + mean) * inv) + b4.w;
    if (write_bf16) {
      short4v o4;
      o4[0] = (short)f2b(y0); o4[1] = (short)f2b(y1);
      o4[2] = (short)f2b(y2); o4[3] = (short)f2b(y3);
      *(short4v*)((unsigned short*)outp + (size_t)row * D_MODEL + c) = o4;
    } else {
      float4 o4 = {y0, y1, y2, y3};
      *(float4*)((float*)outp + (size_t)row * D_MODEL + c) = o4;
    }
  }
}

extern "C" void kernel_launch(void* const* d_in, const int* in_sizes, int n_in,
                              void* d_out, int out_size, void* d_ws, size_t ws_size,
                              hipStream_t stream)
{
  const float* x   = (const float*)d_in[0];
  const float* Wq  = (const float*)d_in[1];
  const float* Wk  = (const float*)d_in[2];
  const float* Wv  = (const float*)d_in[3];
  const float* Wo  = (const float*)d_in[4];
  const float* bo  = (const float*)d_in[5];
  const float* W1  = (const float*)d_in[6];
  const float* b1  = (const float*)d_in[7];
  const float* W2  = (const float*)d_in[8];
  const float* b2  = (const float*)d_in[9];
  const float* g1  = (const float*)d_in[10];
  const float* be1 = (const float*)d_in[11];
  const float* g2  = (const float*)d_in[12];
  const float* be2 = (const float*)d_in[13];
  float* out = (float*)d_out;

  // ws layout (bf16-element offsets; total 104 MiB). vws is V^T [bh][e][s].
  unsigned short* ws     = (unsigned short*)d_ws;
  unsigned short* w1_bt  = ws;
  unsigned short* w2_bt  = ws + 4194304;
  unsigned short* qkv_bt = ws + 8388608;
  unsigned short* wo_bt  = ws + 11534336;
  unsigned short* x_bf   = ws + 12582912;
  unsigned short* qws    = ws + 20971520;
  unsigned short* kws    = ws + 29360128;
  unsigned short* vws    = ws + 37748736;
  unsigned short* ows    = x_bf;                    // overlay x_bf (dead after QKV gemm)
  float*          r1     = (float*)(ws + 20971520); // overlay q+k (dead after attn)
  unsigned short* h1_bf  = x_bf;                    // overlay o (dead after Wo gemm)
  unsigned short* ff1    = ws + 20971520;           // overlay r1+v^T+fresh, 64 MiB

  dim3 blk(256);

  prep_kernel<<<11264, blk, 0, stream>>>(x, x_bf, Wq, Wk, Wv, qkv_bt,
                                         Wo, wo_bt, W1, w1_bt, W2, w2_bt);

  // q,k,v = x @ [Wq|Wk|Wv]  (q scaled log2e/32; v written transposed) -- 256^2 pipeline
  gemm256<<<dim3(3072 / 256, TOKENS / 256), dim3(512), 0, stream>>>(
      x_bf, qkv_bt, nullptr, qws, TOKENS, 3072, 1024, 0);
  // o = attention(q,k,v)
  attn_kernel<<<dim3(SEQ / 128, BATCH * N_HEADS), blk, 0, stream>>>(qws, kws, vws, ows);
  // r1 = x + (o @ Wo + bo)   (fp32)  -- 256x128 pipeline, 256 blocks
  gemm256n<<<dim3(1024 / 128, TOKENS / 256), dim3(512), 0, stream>>>(
      ows, wo_bt, bo, x, nullptr, r1, TOKENS, 1024, 1024, 1);
  // h1 = LN(r1) -> bf16
  ln_kernel<<<TOKENS / 4, blk, 0, stream>>>(r1, g1, be1, h1_bf, 1);
  // ff1 = relu(h1 @ W1 + b1) -> bf16  -- 256^2 pipeline
  gemm256<<<dim3(4096 / 256, TOKENS / 256), dim3(512), 0, stream>>>(
      h1_bf, w1_bt, b1, ff1, TOKENS, 4096, 1024, 2);
  // r2 = h1 + (ff1 @ W2 + b2) -> fp32 into d_out  -- 256x128 pipeline
  gemm256n<<<dim3(1024 / 128, TOKENS / 256), dim3(512), 0, stream>>>(
      ff1, w2_bt, b2, nullptr, h1_bf, out, TOKENS, 1024, 4096, 3);
  // out = LN(r2), in-place fp32
  ln_kernel<<<TOKENS / 4, blk, 0, stream>>>(out, g2, be2, out, 0);
}

// Round 8
// 622.921 us; speedup vs baseline: 1.1386x; 1.1386x over previous
//
#include <hip/hip_runtime.h>

typedef short short8 __attribute__((ext_vector_type(8)));
typedef short short4v __attribute__((ext_vector_type(4)));
typedef float floatx4 __attribute__((ext_vector_type(4)));

#define D_MODEL 1024
#define N_HEADS 16
#define HEAD    64
#define D_FF    4096
#define SEQ     2048
#define BATCH   4
#define TOKENS  (BATCH*SEQ)   // 8192

__device__ __forceinline__ float b2f(unsigned short u) {
  return __uint_as_float(((unsigned)u) << 16);
}
__device__ __forceinline__ unsigned short f2b(float f) {
  unsigned u = __float_as_uint(f);
  unsigned r = 0x7fffu + ((u >> 16) & 1u);
  return (unsigned short)((u + r) >> 16);
}
__device__ __forceinline__ floatx4 mfma16(short8 a, short8 b, floatx4 c) {
  return __builtin_amdgcn_mfma_f32_16x16x32_bf16(a, b, c, 0, 0, 0);
}
__device__ __forceinline__ void load16_lds(const unsigned short* g, unsigned short* l) {
  __builtin_amdgcn_global_load_lds((const __attribute__((address_space(1))) void*)g,
                                   (__attribute__((address_space(3))) void*)l, 16, 0, 0);
}

// ---------------- fused prep: x->bf16, QKV repack, Wo/W1/W2 transpose ----------------
__device__ __forceinline__ void transp_body(
    const float* __restrict__ src, unsigned short* __restrict__ dst,
    int R, int C, int bx, int by, float (*t)[65])
{
  int cb = bx * 64, rb = by * 64;
#pragma unroll
  for (int i = 0; i < 16; i++) {
    int idx = i * 256 + threadIdx.x;
    int lr = idx >> 6, lc = idx & 63;
    t[lr][lc] = src[(size_t)(rb + lr) * C + cb + lc];
  }
  __syncthreads();
#pragma unroll
  for (int i = 0; i < 16; i++) {
    int idx = i * 256 + threadIdx.x;
    int lc = idx >> 6, lr = idx & 63;
    dst[(size_t)(cb + lc) * R + rb + lr] = f2b(t[lr][lc]);
  }
}

__global__ __launch_bounds__(256) void prep_kernel(
    const float* __restrict__ x, unsigned short* __restrict__ x_bf,
    const float* __restrict__ Wq, const float* __restrict__ Wk,
    const float* __restrict__ Wv, unsigned short* __restrict__ qkv_bt,
    const float* __restrict__ Wo, unsigned short* __restrict__ wo_bt,
    const float* __restrict__ W1, unsigned short* __restrict__ w1_bt,
    const float* __restrict__ W2, unsigned short* __restrict__ w2_bt)
{
  __shared__ float t[64][65];
  int bid = blockIdx.x;
  if (bid < 8192) {                       // x fp32 -> bf16
    int idx = bid * 1024 + threadIdx.x * 4;
    float4 v = *(const float4*)(x + idx);
    short4v o;
    o[0] = (short)f2b(v.x); o[1] = (short)f2b(v.y);
    o[2] = (short)f2b(v.z); o[3] = (short)f2b(v.w);
    *(short4v*)(x_bf + idx) = o;
  } else if (bid < 8960) {                // QKV repack: W[h][d][e] -> [c][d]
    int by = bid - 8192;
    int xt = by & 15, z = by >> 4;
    int sel = z >> 4, h = z & 15;
    const float* W = (sel == 0) ? Wq : ((sel == 1) ? Wk : Wv);
    const float* src = W + (size_t)h * D_MODEL * HEAD;
    int rb = xt * 64;
#pragma unroll
    for (int i = 0; i < 16; i++) {
      int idx = i * 256 + threadIdx.x;
      int lr = idx >> 6, lc = idx & 63;
      t[lr][lc] = src[(size_t)(rb + lr) * HEAD + lc];
    }
    __syncthreads();
    unsigned short* d0 = qkv_bt + (size_t)(sel * 1024 + h * 64) * D_MODEL;
#pragma unroll
    for (int i = 0; i < 16; i++) {
      int idx = i * 256 + threadIdx.x;
      int lc = idx >> 6, lr = idx & 63;
      d0[(size_t)lc * D_MODEL + rb + lr] = f2b(t[lr][lc]);
    }
  } else if (bid < 9216) {                // Wo^T
    int i = bid - 8960;
    transp_body(Wo, wo_bt, 1024, 1024, i & 15, i >> 4, t);
  } else if (bid < 10240) {               // W1^T
    int i = bid - 9216;
    transp_body(W1, w1_bt, 1024, 4096, i & 63, i >> 6, t);
  } else {                                // W2^T
    int i = bid - 10240;
    transp_body(W2, w2_bt, 4096, 1024, i & 15, i >> 4, t);
  }
}

// ---------------- 256x256x64 bf16 GEMM, 8-wave 4-phase counted-vmcnt pipeline ------
// Single vmcnt(4) per K-tile at phase 4. Ledger: at tile t ph4, outstanding =
// A1(t+1),B1(t+1),A0(t+2),B0(t+2) = 8 loads; vmcnt(4) retires A1(t+1),B1(t+1)
// and everything older -> all of tile t+1 landed before tile t+1 ph1 reads it.
// WAR: STG into a region is issued >=1 full phase after that region's readers
// drained (lgkmcnt(0) before the MFMA of the reading phase).
// epi 0 = QKV split write (q pre-scaled by log2e/32 for exp2 softmax), epi 2 = relu bf16.
__global__ __launch_bounds__(512, 2) void gemm256(
    const unsigned short* __restrict__ A, const unsigned short* __restrict__ BT,
    const float* __restrict__ biasf, void* __restrict__ outp,
    int M, int N, int K, int epi)
{
  __shared__ unsigned short a_sh[2 * 256 * 64];   // [buf][row][64]
  __shared__ unsigned short b_sh[2 * 256 * 64];   // [buf][permrow][64]

  const int tid  = threadIdx.x;
  const int lane = tid & 63;
  const int wave = tid >> 6;        // 0..7
  const int quad = lane >> 4;
  const int l15  = lane & 15;
  const int wm   = wave >> 2;       // 0..1
  const int wn   = wave & 3;        // 0..3

  // XCD swizzle: M/256 = 32 row-tiles, 4 per XCD (contiguous A band per XCD L2)
  const int lin = blockIdx.y * gridDim.x + blockIdx.x;
  const int xcd = lin & 7, j = lin >> 3;
  const int m0 = (xcd * 4 + (j & 3)) * 256;
  const int n0 = (j >> 2) * 256;

  // staging: thread covers (row u, chunk tid&7) of each 64-row call;
  // source chunk pre-swizzled so LDS content at (r,cc) = logical chunk cc^(r&7)
  const int u  = tid >> 3;                       // 0..63
  const int sc = (tid & 7) ^ (u & 7);
  const unsigned short* a_src = A  + (size_t)(m0 + u) * K + sc * 8;
  const int borig = ((u >> 5) * 64) + (u & 31);  // perm-row -> orig BT row (base)
  const unsigned short* b_src = BT + (size_t)(n0 + borig) * K + sc * 8;
  unsigned short* a_dst = a_sh + wave * 512;     // + buf*16384 + Rc*64
  unsigned short* b_dst = b_sh + wave * 512;

#define SA(T, Rc)  load16_lds(a_src + (size_t)(Rc) * K + (T) * 64, \
                              a_dst + ((T) & 1) * 16384 + (Rc) * 64)
#define SB(T, Rb, Radd) load16_lds(b_src + (size_t)(Radd) * K + (T) * 64, \
                              b_dst + ((T) & 1) * 16384 + (Rb) * 64)
#define STG_A0(T) do { SA(T, 0);   SA(T, 128); } while (0)          // qm=0 rows
#define STG_A1(T) do { SA(T, 64);  SA(T, 192); } while (0)          // qm=1 rows
#define STG_B0(T) do { SB(T, 0, 0);    SB(T, 64, 128); } while (0)  // qn=0 rows
#define STG_B1(T) do { SB(T, 128, 32); SB(T, 192, 160); } while (0) // qn=1 rows

  floatx4 acc[8][4] = {};
  short8 aF[4][2];        // current qm sub-band, both k-halves
  short8 bF[2][2][2];     // [qn][ni][kh] - both qn sets held across the tile
  const unsigned short* ash = a_sh;
  const unsigned short* bsh = b_sh;

#define LDA(QM) \
  _Pragma("unroll") for (int mi = 0; mi < 4; mi++) \
  _Pragma("unroll") for (int kh = 0; kh < 2; kh++) \
    aF[mi][kh] = *(const short8*)(ash + (wm * 128 + (QM) * 64 + mi * 16 + l15) * 64 \
                                  + (((kh * 4 + quad) ^ (l15 & 7)) * 8));
#define LDB(QN) \
  _Pragma("unroll") for (int ni = 0; ni < 2; ni++) \
  _Pragma("unroll") for (int kh = 0; kh < 2; kh++) \
    bF[QN][ni][kh] = *(const short8*)(bsh + ((QN) * 128 + wn * 32 + ni * 16 + l15) * 64 \
                                      + (((kh * 4 + quad) ^ (l15 & 7)) * 8));
#define MM(QM, QN) \
  _Pragma("unroll") for (int mi = 0; mi < 4; mi++) \
  _Pragma("unroll") for (int ni = 0; ni < 2; ni++) { \
    acc[(QM) * 4 + mi][(QN) * 2 + ni] = \
        mfma16(aF[mi][0], bF[QN][ni][0], acc[(QM) * 4 + mi][(QN) * 2 + ni]); \
    acc[(QM) * 4 + mi][(QN) * 2 + ni] = \
        mfma16(aF[mi][1], bF[QN][ni][1], acc[(QM) * 4 + mi][(QN) * 2 + ni]); \
  }
#define PH_VM(N) asm volatile("s_waitcnt vmcnt(" #N ")" ::: "memory");
#define PH_MID() \
  __builtin_amdgcn_s_barrier(); \
  asm volatile("s_waitcnt lgkmcnt(0)" ::: "memory"); \
  __builtin_amdgcn_sched_barrier(0); \
  __builtin_amdgcn_s_setprio(1);
#define PH_END() \
  __builtin_amdgcn_s_setprio(0); \
  __builtin_amdgcn_s_barrier();

  const int NT = K >> 6;

  // prologue: tile0 fully + tile1 first-needed halves
  STG_A0(0); STG_B0(0); STG_A1(0); STG_B1(0); STG_A0(1); STG_B0(1);
  PH_VM(4)                                           // retire all of tile 0
  __builtin_amdgcn_s_barrier();

  for (int t = 0; t < NT - 2; ++t) {
    ash = a_sh + (t & 1) * 16384;
    bsh = b_sh + (t & 1) * 16384;

    LDA(0) LDB(0)
    STG_A1(t + 1);
    PH_MID() MM(0, 0) PH_END();

    LDB(1)
    STG_B1(t + 1);
    PH_MID() MM(0, 1) PH_END();

    LDA(1)
    STG_A0(t + 2);
    PH_MID() MM(1, 0) PH_END();

    STG_B0(t + 2);
    PH_VM(4)
    PH_MID() MM(1, 1) PH_END();
  }
  {// tile NT-2: no t+2 staging; drain toward tail
    const int t = NT - 2;
    ash = a_sh + (t & 1) * 16384;
    bsh = b_sh + (t & 1) * 16384;

    LDA(0) LDB(0)
    STG_A1(t + 1);
    PH_MID() MM(0, 0) PH_END();

    LDB(1)
    STG_B1(t + 1);
    PH_MID() MM(0, 1) PH_END();

    LDA(1)
    PH_MID() MM(1, 0) PH_END();

    PH_VM(0)
    PH_MID() MM(1, 1) PH_END();
  }
  {// tile NT-1: final tile, no staging, no waits needed
    const int t = NT - 1;
    ash = a_sh + (t & 1) * 16384;
    bsh = b_sh + (t & 1) * 16384;

    LDA(0) LDB(0)
    PH_MID() MM(0, 0) PH_END();

    LDB(1)
    PH_MID() MM(0, 1) PH_END();

    LDA(1)
    PH_MID() MM(1, 0) PH_END();

    PH_MID() MM(1, 1) PH_END();
  }

#undef SA
#undef SB
#undef STG_A0
#undef STG_A1
#undef STG_B0
#undef STG_B1
#undef LDA
#undef LDB
#undef MM
#undef PH_VM
#undef PH_MID
#undef PH_END

#pragma unroll
  for (int mi = 0; mi < 8; mi++) {
#pragma unroll
    for (int ni = 0; ni < 4; ni++) {
      const int col = n0 + wn * 64 + ni * 16 + l15;
      const int row0 = m0 + wm * 128 + mi * 16 + quad * 4;
      if (epi == 0) {
        int sel = col >> 10;
        int cc = col & 1023;
        int h = cc >> 6, e = cc & 63;
        int b = row0 >> 11, s0 = row0 & 2047;
        if (sel < 2) {
          unsigned short* base = (unsigned short*)outp + (size_t)sel * 8388608;
#pragma unroll
          for (int r = 0; r < 4; r++) {
            // q scaled by log2e/sqrt(D_MODEL) so attn can use native exp2
            float v2 = (sel == 0) ? acc[mi][ni][r] * 0.04508422f : acc[mi][ni][r];
            base[((size_t)((b * N_HEADS + h) * SEQ + (s0 + r))) * HEAD + e] = f2b(v2);
          }
        } else {
          unsigned short* base = (unsigned short*)outp + (size_t)2 * 8388608;
          short4v pk;
#pragma unroll
          for (int r = 0; r < 4; r++) pk[r] = (short)f2b(acc[mi][ni][r]);
          *(short4v*)(base + ((size_t)((b * N_HEADS + h) * HEAD + e)) * SEQ + s0) = pk;
        }
      } else {  // epi 2: relu -> bf16
#pragma unroll
        for (int r = 0; r < 4; r++)
          ((unsigned short*)outp)[(size_t)(row0 + r) * N + col] =
              f2b(fmaxf(acc[mi][ni][r] + biasf[col], 0.0f));
      }
    }
  }
}

// ---------------- 256x128x64 bf16 GEMM, 8-wave 2-phase counted-vmcnt pipeline ------
// For the N=1024 GEMMs (Wo, W2): grid 32x8 = 256 blocks = 1/CU, 512 thr = 8 waves
// (4M x 2N, 64x64 per wave). LDS 96 KiB: A 2x[256][64], B 2x[128][64], chunk-XOR
// swizzled (content at (r,cc) = logical chunk cc^(r&7), staged via pre-swizzled src).
// 2 phases/K-tile, 16 MFMA each; counted vmcnt(4) once per tile.
// epi 1: fp32 out = acc + biasf[col] + residf[row*N+col]
// epi 3: fp32 out = acc + biasf[col] + b2f(residb[row*N+col])
__global__ __launch_bounds__(512, 2) void gemm256n(
    const unsigned short* __restrict__ A, const unsigned short* __restrict__ BT,
    const float* __restrict__ biasf, const float* __restrict__ residf,
    const unsigned short* __restrict__ residb, void* __restrict__ outp,
    int M, int N, int K, int epi)
{
  __shared__ unsigned short a_sh[2 * 256 * 64];   // 64 KiB
  __shared__ unsigned short b_sh[2 * 128 * 64];   // 32 KiB

  const int tid  = threadIdx.x;
  const int lane = tid & 63;
  const int wave = tid >> 6;        // 0..7
  const int quad = lane >> 4;
  const int l15  = lane & 15;
  const int wm   = wave >> 1;       // 0..3
  const int wn   = wave & 1;        // 0..1

  // XCD swizzle: 32 row-tiles, 4 per XCD; 8 col-tiles
  const int lin = blockIdx.y * gridDim.x + blockIdx.x;
  const int xcd = lin & 7, j = lin >> 3;
  const int m0 = (xcd * 4 + (j & 3)) * 256;
  const int n0 = (j >> 2) * 128;

  const int u  = tid >> 3;                       // 0..63
  const int sc = (tid & 7) ^ (u & 7);
  const unsigned short* a_src = A  + (size_t)(m0 + u) * K + sc * 8;
  const unsigned short* b_src = BT + (size_t)(n0 + u) * K + sc * 8;
  unsigned short* a_dst = a_sh + wave * 512;
  unsigned short* b_dst = b_sh + wave * 512;

#define SA(T, Rc) load16_lds(a_src + (size_t)(Rc) * K + (T) * 64, \
                             a_dst + ((T) & 1) * 16384 + (Rc) * 64)
#define SB(T, Rb) load16_lds(b_src + (size_t)(Rb) * K + (T) * 64, \
                             b_dst + ((T) & 1) * 8192 + (Rb) * 64)
#define STG_A0(T) do { SA(T, 0);   SA(T, 64);  } while (0)   // rows 0..127
#define STG_A1(T) do { SA(T, 128); SA(T, 192); } while (0)   // rows 128..255
#define STG_B(T)  do { SB(T, 0);   SB(T, 64);  } while (0)   // all 128 B rows

  floatx4 acc[4][4] = {};
  short8 aF[2][2];        // current QM: [mi][kh]
  short8 bF[2][2][2];     // [QN][ni][kh] - held across the tile
  const unsigned short* ash = a_sh;
  const unsigned short* bsh = b_sh;

#define LDA(QM) \
  _Pragma("unroll") for (int mi = 0; mi < 2; mi++) \
  _Pragma("unroll") for (int kh = 0; kh < 2; kh++) \
    aF[mi][kh] = *(const short8*)(ash + ((QM) * 128 + wm * 32 + mi * 16 + l15) * 64 \
                                  + (((kh * 4 + quad) ^ (l15 & 7)) * 8));
#define LDB(QN) \
  _Pragma("unroll") for (int ni = 0; ni < 2; ni++) \
  _Pragma("unroll") for (int kh = 0; kh < 2; kh++) \
    bF[QN][ni][kh] = *(const short8*)(bsh + ((QN) * 64 + wn * 32 + ni * 16 + l15) * 64 \
                                      + (((kh * 4 + quad) ^ (l15 & 7)) * 8));
#define MM2(QM) \
  _Pragma("unroll") for (int qn = 0; qn < 2; qn++) \
  _Pragma("unroll") for (int mi = 0; mi < 2; mi++) \
  _Pragma("unroll") for (int ni = 0; ni < 2; ni++) { \
    acc[(QM) * 2 + mi][qn * 2 + ni] = \
        mfma16(aF[mi][0], bF[qn][ni][0], acc[(QM) * 2 + mi][qn * 2 + ni]); \
    acc[(QM) * 2 + mi][qn * 2 + ni] = \
        mfma16(aF[mi][1], bF[qn][ni][1], acc[(QM) * 2 + mi][qn * 2 + ni]); \
  }
#define PH_VM(N) asm volatile("s_waitcnt vmcnt(" #N ")" ::: "memory");
#define PH_MID() \
  __builtin_amdgcn_s_barrier(); \
  asm volatile("s_waitcnt lgkmcnt(0)" ::: "memory"); \
  __builtin_amdgcn_sched_barrier(0); \
  __builtin_amdgcn_s_setprio(1);
#define PH_END() \
  __builtin_amdgcn_s_setprio(0); \
  __builtin_amdgcn_s_barrier();

  const int NT = K >> 6;

  // prologue: tile0 fully + tile1 ph1-needed regions
  STG_A0(0); STG_B(0); STG_A1(0); STG_A0(1); STG_B(1);
  PH_VM(4)                            // retire all 6 of tile 0; keep A0(1),B(1)
  __builtin_amdgcn_s_barrier();

  for (int t = 0; t < NT - 2; ++t) {
    ash = a_sh + (t & 1) * 16384;
    bsh = b_sh + (t & 1) * 8192;

    LDA(0) LDB(0) LDB(1)
    STG_A1(t + 1);
    PH_MID() MM2(0) PH_END();

    LDA(1)
    STG_A0(t + 2); STG_B(t + 2);
    PH_VM(4)
    PH_MID() MM2(1) PH_END();
  }
  {// tile NT-2: stage only A1(NT-1); drain
    const int t = NT - 2;
    ash = a_sh + (t & 1) * 16384;
    bsh = b_sh + (t & 1) * 8192;

    LDA(0) LDB(0) LDB(1)
    STG_A1(t + 1);
    PH_MID() MM2(0) PH_END();

    LDA(1)
    PH_VM(0)
    PH_MID() MM2(1) PH_END();
  }
  {// tile NT-1: no staging
    const int t = NT - 1;
    ash = a_sh + (t & 1) * 16384;
    bsh = b_sh + (t & 1) * 8192;

    LDA(0) LDB(0) LDB(1)
    PH_MID() MM2(0) PH_END();

    LDA(1)
    PH_MID() MM2(1) PH_END();
  }

#undef SA
#undef SB
#undef STG_A0
#undef STG_A1
#undef STG_B
#undef LDA
#undef LDB
#undef MM2
#undef PH_VM
#undef PH_MID
#undef PH_END

#pragma unroll
  for (int am = 0; am < 4; am++) {
    const int row0 = m0 + (am >> 1) * 128 + wm * 32 + (am & 1) * 16 + quad * 4;
#pragma unroll
    for (int bn = 0; bn < 4; bn++) {
      const int col = n0 + (bn >> 1) * 64 + wn * 32 + (bn & 1) * 16 + l15;
      if (epi == 1) {
#pragma unroll
        for (int r = 0; r < 4; r++)
          ((float*)outp)[(size_t)(row0 + r) * N + col] =
              acc[am][bn][r] + biasf[col] + residf[(size_t)(row0 + r) * N + col];
      } else {
#pragma unroll
        for (int r = 0; r < 4; r++)
          ((float*)outp)[(size_t)(row0 + r) * N + col] =
              acc[am][bn][r] + biasf[col] + b2f(residb[(size_t)(row0 + r) * N + col]);
      }
    }
  }
}

// ---------------- flash attention v3: S^T, exp2 + MFMA row-sum, NO K/V staging ------
// R7 post-mortem: launch_bounds(256,6) capped VGPR at ~85 -> compiler spilled the
// accumulators to scratch (VGPR_Count 40, WRITE_SIZE 288 MB, 335 us). The
// no-staging structure itself was never tested. Fix: (256,4) -> 128-VGPR budget
// (kernel needs ~110), no spill, 4 blocks/CU (16 waves) -- same occupancy as the
// verified R4 staged version, clean A/B of the structure.
// Structure: K and V fragments are IDENTICAL across the 4 waves -> per-CU L1
// dedupes the redundant wave reads; no K/V LDS, no __syncthreads at all (p_sh is
// wave-private). bh-clustered XCD swizzle keeps one bh's K/V resident per XCD L2.
__global__ __launch_bounds__(256, 4) void attn_kernel(
    const unsigned short* __restrict__ q, const unsigned short* __restrict__ k,
    const unsigned short* __restrict__ vt, unsigned short* __restrict__ o)
{
  // bijective bh-clustering swizzle: lin = g*8 + xcd; qt = g&15; bh = (g>>4)*8 + xcd
  const int lin = blockIdx.y * gridDim.x + blockIdx.x;   // gridDim.x = 16
  const int xcd = lin & 7, g = lin >> 3;
  const int qt = g & 15;
  const int bh = (g >> 4) * 8 + xcd;

  const int tid = threadIdx.x, lane = tid & 63, wave = tid >> 6;
  const int quad = lane >> 4, l15 = lane & 15;
  const size_t base = (size_t)bh * SEQ * HEAD;

  __shared__ unsigned short p_sh[4 * 32 * 72];
  unsigned short* pw = p_sh + wave * 32 * 72;  // wave-private P [m 32][t 64+pad]

  short8 qf[2][2];
#pragma unroll
  for (int mj = 0; mj < 2; mj++) {
    const unsigned short* qp =
        q + base + (size_t)(qt * 128 + wave * 32 + mj * 16 + l15) * HEAD;
    qf[mj][0] = *(const short8*)(qp + quad * 8);
    qf[mj][1] = *(const short8*)(qp + 32 + quad * 8);
  }

  floatx4 oacc[2][4] = {};
  floatx4 rsacc[2] = {};   // row sums live in col 0 (lanes with l15==0)

  // ones B-fragment: B[row 0][k] = 1.0bf16, rows 1..15 = 0
  short8 onesf;
  {
    short ov = (l15 == 0) ? (short)0x3F80 : (short)0;
#pragma unroll
    for (int jj = 0; jj < 8; jj++) onesf[jj] = ov;
  }

  for (int kt = 0; kt < SEQ / 64; kt++) {
    const unsigned short* kb = k + base + (size_t)kt * 64 * HEAD;
    const unsigned short* vb = vt + base + (size_t)kt * 64;

    // S^T tile: A = K rows (t) straight from global, B = Q rows (m)
#pragma unroll
    for (int ti = 0; ti < 4; ti++) {
      int t = ti * 16 + l15;
      short8 kf0 = *(const short8*)(kb + (size_t)t * HEAD + quad * 8);
      short8 kf1 = *(const short8*)(kb + (size_t)t * HEAD + 32 + quad * 8);
      floatx4 s0 = {0.f, 0.f, 0.f, 0.f}, s1 = {0.f, 0.f, 0.f, 0.f};
      __builtin_amdgcn_s_setprio(1);
      s0 = mfma16(kf0, qf[0][0], s0);
      s0 = mfma16(kf1, qf[0][1], s0);
      s1 = mfma16(kf0, qf[1][0], s1);
      s1 = mfma16(kf1, qf[1][1], s1);
      __builtin_amdgcn_s_setprio(0);
#pragma unroll
      for (int mj = 0; mj < 2; mj++) {
        floatx4 s = mj ? s1 : s0;
        float p0 = __builtin_amdgcn_exp2f(s[0]);
        float p1 = __builtin_amdgcn_exp2f(s[1]);
        float p2 = __builtin_amdgcn_exp2f(s[2]);
        float p3 = __builtin_amdgcn_exp2f(s[3]);
        uint2 u;
        u.x = __builtin_amdgcn_perm(__float_as_uint(p1), __float_as_uint(p0), 0x07060302u);
        u.y = __builtin_amdgcn_perm(__float_as_uint(p3), __float_as_uint(p2), 0x07060302u);
        *(uint2*)(pw + (mj * 16 + l15) * 72 + ti * 16 + quad * 4) = u;
      }
    }

    // O += P @ V   (A = P[m][t], B = V^T[e][t] straight from global); rs += P @ 1
    {
      short8 pf[2][2];
#pragma unroll
      for (int mj = 0; mj < 2; mj++) {
        pf[mj][0] = *(const short8*)(pw + (mj * 16 + l15) * 72 + quad * 8);
        pf[mj][1] = *(const short8*)(pw + (mj * 16 + l15) * 72 + 32 + quad * 8);
      }
      __builtin_amdgcn_s_setprio(1);
#pragma unroll
      for (int ni = 0; ni < 4; ni++) {
        int e = ni * 16 + l15;
        short8 bv0 = *(const short8*)(vb + (size_t)e * SEQ + quad * 8);
        short8 bv1 = *(const short8*)(vb + (size_t)e * SEQ + 32 + quad * 8);
#pragma unroll
        for (int mj = 0; mj < 2; mj++) {
          oacc[mj][ni] = mfma16(pf[mj][0], bv0, oacc[mj][ni]);
          oacc[mj][ni] = mfma16(pf[mj][1], bv1, oacc[mj][ni]);
        }
      }
#pragma unroll
      for (int mj = 0; mj < 2; mj++) {
        rsacc[mj] = mfma16(pf[mj][0], onesf, rsacc[mj]);
        rsacc[mj] = mfma16(pf[mj][1], onesf, rsacc[mj]);
      }
      __builtin_amdgcn_s_setprio(0);
    }
  }

  const int b = bh >> 4, h = bh & 15;
#pragma unroll
  for (int mj = 0; mj < 2; mj++)
#pragma unroll
    for (int r = 0; r < 4; r++) {
      int s = qt * 128 + wave * 32 + mj * 16 + quad * 4 + r;
      // rs for row m=quad*4+r sits in lane quad*16 (l15==0), element r
      float rsv = __shfl(rsacc[mj][r], quad * 16, 64);
      float inv = 1.0f / rsv;
#pragma unroll
      for (int ni = 0; ni < 4; ni++)
        o[((size_t)(b * SEQ + s)) * D_MODEL + h * HEAD + ni * 16 + l15] =
            f2b(oacc[mj][ni][r] * inv);
    }
}

// ---------------- layernorm: wave-per-row, no LDS/barrier ----------------
__global__ __launch_bounds__(256) void ln_kernel(
    const float* __restrict__ in, const float* __restrict__ g,
    const float* __restrict__ be, void* __restrict__ outp, int write_bf16)
{
  const int row = blockIdx.x * 4 + (threadIdx.x >> 6);
  const int lane = threadIdx.x & 63;
  const float* xp = in + (size_t)row * D_MODEL;
  float4 xv[4];
  float s = 0.0f, ss = 0.0f;
#pragma unroll
  for (int j = 0; j < 4; j++) {
    xv[j] = *(const float4*)(xp + j * 256 + lane * 4);
    s += (xv[j].x + xv[j].y) + (xv[j].z + xv[j].w);
    ss += (xv[j].x * xv[j].x + xv[j].y * xv[j].y) +
          (xv[j].z * xv[j].z + xv[j].w * xv[j].w);
  }
#pragma unroll
  for (int m = 1; m < 64; m <<= 1) {
    s += __shfl_xor(s, m, 64);
    ss += __shfl_xor(ss, m, 64);
  }
  float mean = s * (1.0f / 1024.0f);
  float var = fmaxf((ss - 1024.0f * mean * mean) * (1.0f / 1023.0f), 0.0f);
  float inv = 1.0f / (sqrtf(var) + 1e-6f);
#pragma unroll
  for (int j = 0; j < 4; j++) {
    int c = j * 256 + lane * 4;
    float4 g4 = *(const float4*)(g + c);
    float4 b4 = *(const float4*)(be + c);
    float y0 = g4.x * ((xv[j].x + mean) * inv) + b4.x;
    float y1 = g4.y * ((xv[j].y + mean) * inv) + b4.y;
    float y2 = g4.z * ((xv[j].z + mean) * inv) + b4.z;
    float y3 = g4.w * ((xv[j].w + mean) * inv) + b4.w;
    if (write_bf16) {
      short4v o4;
      o4[0] = (short)f2b(y0); o4[1] = (short)f2b(y1);
      o4[2] = (short)f2b(y2); o4[3] = (short)f2b(y3);
      *(short4v*)((unsigned short*)outp + (size_t)row * D_MODEL + c) = o4;
    } else {
      float4 o4 = {y0, y1, y2, y3};
      *(float4*)((float*)outp + (size_t)row * D_MODEL + c) = o4;
    }
  }
}

extern "C" void kernel_launch(void* const* d_in, const int* in_sizes, int n_in,
                              void* d_out, int out_size, void* d_ws, size_t ws_size,
                              hipStream_t stream)
{
  const float* x   = (const float*)d_in[0];
  const float* Wq  = (const float*)d_in[1];
  const float* Wk  = (const float*)d_in[2];
  const float* Wv  = (const float*)d_in[3];
  const float* Wo  = (const float*)d_in[4];
  const float* bo  = (const float*)d_in[5];
  const float* W1  = (const float*)d_in[6];
  const float* b1  = (const float*)d_in[7];
  const float* W2  = (const float*)d_in[8];
  const float* b2  = (const float*)d_in[9];
  const float* g1  = (const float*)d_in[10];
  const float* be1 = (const float*)d_in[11];
  const float* g2  = (const float*)d_in[12];
  const float* be2 = (const float*)d_in[13];
  float* out = (float*)d_out;

  // ws layout (bf16-element offsets; total 104 MiB). vws is V^T [bh][e][s].
  unsigned short* ws     = (unsigned short*)d_ws;
  unsigned short* w1_bt  = ws;
  unsigned short* w2_bt  = ws + 4194304;
  unsigned short* qkv_bt = ws + 8388608;
  unsigned short* wo_bt  = ws + 11534336;
  unsigned short* x_bf   = ws + 12582912;
  unsigned short* qws    = ws + 20971520;
  unsigned short* kws    = ws + 29360128;
  unsigned short* vws    = ws + 37748736;
  unsigned short* ows    = x_bf;                    // overlay x_bf (dead after QKV gemm)
  float*          r1     = (float*)(ws + 20971520); // overlay q+k (dead after attn)
  unsigned short* h1_bf  = x_bf;                    // overlay o (dead after Wo gemm)
  unsigned short* ff1    = ws + 20971520;           // overlay r1+v^T+fresh, 64 MiB

  dim3 blk(256);

  prep_kernel<<<11264, blk, 0, stream>>>(x, x_bf, Wq, Wk, Wv, qkv_bt,
                                         Wo, wo_bt, W1, w1_bt, W2, w2_bt);

  // q,k,v = x @ [Wq|Wk|Wv]  (q scaled log2e/32; v written transposed) -- 256^2 pipeline
  gemm256<<<dim3(3072 / 256, TOKENS / 256), dim3(512), 0, stream>>>(
      x_bf, qkv_bt, nullptr, qws, TOKENS, 3072, 1024, 0);
  // o = attention(q,k,v)
  attn_kernel<<<dim3(SEQ / 128, BATCH * N_HEADS), blk, 0, stream>>>(qws, kws, vws, ows);
  // r1 = x + (o @ Wo + bo)   (fp32)  -- 256x128 pipeline, 256 blocks
  gemm256n<<<dim3(1024 / 128, TOKENS / 256), dim3(512), 0, stream>>>(
      ows, wo_bt, bo, x, nullptr, r1, TOKENS, 1024, 1024, 1);
  // h1 = LN(r1) -> bf16
  ln_kernel<<<TOKENS / 4, blk, 0, stream>>>(r1, g1, be1, h1_bf, 1);
  // ff1 = relu(h1 @ W1 + b1) -> bf16  -- 256^2 pipeline
  gemm256<<<dim3(4096 / 256, TOKENS / 256), dim3(512), 0, stream>>>(
      h1_bf, w1_bt, b1, ff1, TOKENS, 4096, 1024, 2);
  // r2 = h1 + (ff1 @ W2 + b2) -> fp32 into d_out  -- 256x128 pipeline
  gemm256n<<<dim3(1024 / 128, TOKENS / 256), dim3(512), 0, stream>>>(
      ff1, w2_bt, b2, nullptr, h1_bf, out, TOKENS, 1024, 4096, 3);
  // out = LN(r2), in-place fp32
  ln_kernel<<<TOKENS / 4, blk, 0, stream>>>(out, g2, be2, out, 0);
}

// Round 9
// 468.947 us; speedup vs baseline: 1.5125x; 1.3283x over previous
//
#include <hip/hip_runtime.h>

typedef short short8 __attribute__((ext_vector_type(8)));
typedef short short4v __attribute__((ext_vector_type(4)));
typedef float floatx4 __attribute__((ext_vector_type(4)));

#define D_MODEL 1024
#define N_HEADS 16
#define HEAD    64
#define D_FF    4096
#define SEQ     2048
#define BATCH   4
#define TOKENS  (BATCH*SEQ)   // 8192

__device__ __forceinline__ float b2f(unsigned short u) {
  return __uint_as_float(((unsigned)u) << 16);
}
__device__ __forceinline__ unsigned short f2b(float f) {
  unsigned u = __float_as_uint(f);
  unsigned r = 0x7fffu + ((u >> 16) & 1u);
  return (unsigned short)((u + r) >> 16);
}
__device__ __forceinline__ floatx4 mfma16(short8 a, short8 b, floatx4 c) {
  return __builtin_amdgcn_mfma_f32_16x16x32_bf16(a, b, c, 0, 0, 0);
}
__device__ __forceinline__ void load16_lds(const unsigned short* g, unsigned short* l) {
  __builtin_amdgcn_global_load_lds((const __attribute__((address_space(1))) void*)g,
                                   (__attribute__((address_space(3))) void*)l, 16, 0, 0);
}

// ---------------- fused prep: x->bf16, QKV repack, Wo/W1/W2 transpose ----------------
__device__ __forceinline__ void transp_body(
    const float* __restrict__ src, unsigned short* __restrict__ dst,
    int R, int C, int bx, int by, float (*t)[65])
{
  int cb = bx * 64, rb = by * 64;
#pragma unroll
  for (int i = 0; i < 16; i++) {
    int idx = i * 256 + threadIdx.x;
    int lr = idx >> 6, lc = idx & 63;
    t[lr][lc] = src[(size_t)(rb + lr) * C + cb + lc];
  }
  __syncthreads();
#pragma unroll
  for (int i = 0; i < 16; i++) {
    int idx = i * 256 + threadIdx.x;
    int lc = idx >> 6, lr = idx & 63;
    dst[(size_t)(cb + lc) * R + rb + lr] = f2b(t[lr][lc]);
  }
}

__global__ __launch_bounds__(256) void prep_kernel(
    const float* __restrict__ x, unsigned short* __restrict__ x_bf,
    const float* __restrict__ Wq, const float* __restrict__ Wk,
    const float* __restrict__ Wv, unsigned short* __restrict__ qkv_bt,
    const float* __restrict__ Wo, unsigned short* __restrict__ wo_bt,
    const float* __restrict__ W1, unsigned short* __restrict__ w1_bt,
    const float* __restrict__ W2, unsigned short* __restrict__ w2_bt)
{
  __shared__ float t[64][65];
  int bid = blockIdx.x;
  if (bid < 8192) {                       // x fp32 -> bf16
    int idx = bid * 1024 + threadIdx.x * 4;
    float4 v = *(const float4*)(x + idx);
    short4v o;
    o[0] = (short)f2b(v.x); o[1] = (short)f2b(v.y);
    o[2] = (short)f2b(v.z); o[3] = (short)f2b(v.w);
    *(short4v*)(x_bf + idx) = o;
  } else if (bid < 8960) {                // QKV repack: W[h][d][e] -> [c][d]
    int by = bid - 8192;
    int xt = by & 15, z = by >> 4;
    int sel = z >> 4, h = z & 15;
    const float* W = (sel == 0) ? Wq : ((sel == 1) ? Wk : Wv);
    const float* src = W + (size_t)h * D_MODEL * HEAD;
    int rb = xt * 64;
#pragma unroll
    for (int i = 0; i < 16; i++) {
      int idx = i * 256 + threadIdx.x;
      int lr = idx >> 6, lc = idx & 63;
      t[lr][lc] = src[(size_t)(rb + lr) * HEAD + lc];
    }
    __syncthreads();
    unsigned short* d0 = qkv_bt + (size_t)(sel * 1024 + h * 64) * D_MODEL;
#pragma unroll
    for (int i = 0; i < 16; i++) {
      int idx = i * 256 + threadIdx.x;
      int lc = idx >> 6, lr = idx & 63;
      d0[(size_t)lc * D_MODEL + rb + lr] = f2b(t[lr][lc]);
    }
  } else if (bid < 9216) {                // Wo^T
    int i = bid - 8960;
    transp_body(Wo, wo_bt, 1024, 1024, i & 15, i >> 4, t);
  } else if (bid < 10240) {               // W1^T
    int i = bid - 9216;
    transp_body(W1, w1_bt, 1024, 4096, i & 63, i >> 6, t);
  } else {                                // W2^T
    int i = bid - 10240;
    transp_body(W2, w2_bt, 4096, 1024, i & 15, i >> 4, t);
  }
}

// ---------------- 256x256x64 bf16 GEMM, 8-wave 4-phase counted-vmcnt pipeline ------
// Single vmcnt(4) per K-tile at phase 4. Ledger: at tile t ph4, outstanding =
// A1(t+1),B1(t+1),A0(t+2),B0(t+2) = 8 loads; vmcnt(4) retires A1(t+1),B1(t+1)
// and everything older -> all of tile t+1 landed before tile t+1 ph1 reads it.
// WAR: STG into a region is issued >=1 full phase after that region's readers
// drained (lgkmcnt(0) before the MFMA of the reading phase).
// epi 0 = QKV split write (q pre-scaled by log2e/32 for exp2 softmax), epi 2 = relu bf16.
__global__ __launch_bounds__(512, 2) void gemm256(
    const unsigned short* __restrict__ A, const unsigned short* __restrict__ BT,
    const float* __restrict__ biasf, void* __restrict__ outp,
    int M, int N, int K, int epi)
{
  __shared__ unsigned short a_sh[2 * 256 * 64];   // [buf][row][64]
  __shared__ unsigned short b_sh[2 * 256 * 64];   // [buf][permrow][64]

  const int tid  = threadIdx.x;
  const int lane = tid & 63;
  const int wave = tid >> 6;        // 0..7
  const int quad = lane >> 4;
  const int l15  = lane & 15;
  const int wm   = wave >> 2;       // 0..1
  const int wn   = wave & 3;        // 0..3

  // XCD swizzle: M/256 = 32 row-tiles, 4 per XCD (contiguous A band per XCD L2)
  const int lin = blockIdx.y * gridDim.x + blockIdx.x;
  const int xcd = lin & 7, j = lin >> 3;
  const int m0 = (xcd * 4 + (j & 3)) * 256;
  const int n0 = (j >> 2) * 256;

  // staging: thread covers (row u, chunk tid&7) of each 64-row call;
  // source chunk pre-swizzled so LDS content at (r,cc) = logical chunk cc^(r&7)
  const int u  = tid >> 3;                       // 0..63
  const int sc = (tid & 7) ^ (u & 7);
  const unsigned short* a_src = A  + (size_t)(m0 + u) * K + sc * 8;
  const int borig = ((u >> 5) * 64) + (u & 31);  // perm-row -> orig BT row (base)
  const unsigned short* b_src = BT + (size_t)(n0 + borig) * K + sc * 8;
  unsigned short* a_dst = a_sh + wave * 512;     // + buf*16384 + Rc*64
  unsigned short* b_dst = b_sh + wave * 512;

#define SA(T, Rc)  load16_lds(a_src + (size_t)(Rc) * K + (T) * 64, \
                              a_dst + ((T) & 1) * 16384 + (Rc) * 64)
#define SB(T, Rb, Radd) load16_lds(b_src + (size_t)(Radd) * K + (T) * 64, \
                              b_dst + ((T) & 1) * 16384 + (Rb) * 64)
#define STG_A0(T) do { SA(T, 0);   SA(T, 128); } while (0)          // qm=0 rows
#define STG_A1(T) do { SA(T, 64);  SA(T, 192); } while (0)          // qm=1 rows
#define STG_B0(T) do { SB(T, 0, 0);    SB(T, 64, 128); } while (0)  // qn=0 rows
#define STG_B1(T) do { SB(T, 128, 32); SB(T, 192, 160); } while (0) // qn=1 rows

  floatx4 acc[8][4] = {};
  short8 aF[4][2];        // current qm sub-band, both k-halves
  short8 bF[2][2][2];     // [qn][ni][kh] - both qn sets held across the tile
  const unsigned short* ash = a_sh;
  const unsigned short* bsh = b_sh;

#define LDA(QM) \
  _Pragma("unroll") for (int mi = 0; mi < 4; mi++) \
  _Pragma("unroll") for (int kh = 0; kh < 2; kh++) \
    aF[mi][kh] = *(const short8*)(ash + (wm * 128 + (QM) * 64 + mi * 16 + l15) * 64 \
                                  + (((kh * 4 + quad) ^ (l15 & 7)) * 8));
#define LDB(QN) \
  _Pragma("unroll") for (int ni = 0; ni < 2; ni++) \
  _Pragma("unroll") for (int kh = 0; kh < 2; kh++) \
    bF[QN][ni][kh] = *(const short8*)(bsh + ((QN) * 128 + wn * 32 + ni * 16 + l15) * 64 \
                                      + (((kh * 4 + quad) ^ (l15 & 7)) * 8));
#define MM(QM, QN) \
  _Pragma("unroll") for (int mi = 0; mi < 4; mi++) \
  _Pragma("unroll") for (int ni = 0; ni < 2; ni++) { \
    acc[(QM) * 4 + mi][(QN) * 2 + ni] = \
        mfma16(aF[mi][0], bF[QN][ni][0], acc[(QM) * 4 + mi][(QN) * 2 + ni]); \
    acc[(QM) * 4 + mi][(QN) * 2 + ni] = \
        mfma16(aF[mi][1], bF[QN][ni][1], acc[(QM) * 4 + mi][(QN) * 2 + ni]); \
  }
#define PH_VM(N) asm volatile("s_waitcnt vmcnt(" #N ")" ::: "memory");
#define PH_MID() \
  __builtin_amdgcn_s_barrier(); \
  asm volatile("s_waitcnt lgkmcnt(0)" ::: "memory"); \
  __builtin_amdgcn_sched_barrier(0); \
  __builtin_amdgcn_s_setprio(1);
#define PH_END() \
  __builtin_amdgcn_s_setprio(0); \
  __builtin_amdgcn_s_barrier();

  const int NT = K >> 6;

  // prologue: tile0 fully + tile1 first-needed halves
  STG_A0(0); STG_B0(0); STG_A1(0); STG_B1(0); STG_A0(1); STG_B0(1);
  PH_VM(4)                                           // retire all of tile 0
  __builtin_amdgcn_s_barrier();

  for (int t = 0; t < NT - 2; ++t) {
    ash = a_sh + (t & 1) * 16384;
    bsh = b_sh + (t & 1) * 16384;

    LDA(0) LDB(0)
    STG_A1(t + 1);
    PH_MID() MM(0, 0) PH_END();

    LDB(1)
    STG_B1(t + 1);
    PH_MID() MM(0, 1) PH_END();

    LDA(1)
    STG_A0(t + 2);
    PH_MID() MM(1, 0) PH_END();

    STG_B0(t + 2);
    PH_VM(4)
    PH_MID() MM(1, 1) PH_END();
  }
  {// tile NT-2: no t+2 staging; drain toward tail
    const int t = NT - 2;
    ash = a_sh + (t & 1) * 16384;
    bsh = b_sh + (t & 1) * 16384;

    LDA(0) LDB(0)
    STG_A1(t + 1);
    PH_MID() MM(0, 0) PH_END();

    LDB(1)
    STG_B1(t + 1);
    PH_MID() MM(0, 1) PH_END();

    LDA(1)
    PH_MID() MM(1, 0) PH_END();

    PH_VM(0)
    PH_MID() MM(1, 1) PH_END();
  }
  {// tile NT-1: final tile, no staging, no waits needed
    const int t = NT - 1;
    ash = a_sh + (t & 1) * 16384;
    bsh = b_sh + (t & 1) * 16384;

    LDA(0) LDB(0)
    PH_MID() MM(0, 0) PH_END();

    LDB(1)
    PH_MID() MM(0, 1) PH_END();

    LDA(1)
    PH_MID() MM(1, 0) PH_END();

    PH_MID() MM(1, 1) PH_END();
  }

#undef SA
#undef SB
#undef STG_A0
#undef STG_A1
#undef STG_B0
#undef STG_B1
#undef LDA
#undef LDB
#undef MM
#undef PH_VM
#undef PH_MID
#undef PH_END

#pragma unroll
  for (int mi = 0; mi < 8; mi++) {
#pragma unroll
    for (int ni = 0; ni < 4; ni++) {
      const int col = n0 + wn * 64 + ni * 16 + l15;
      const int row0 = m0 + wm * 128 + mi * 16 + quad * 4;
      if (epi == 0) {
        int sel = col >> 10;
        int cc = col & 1023;
        int h = cc >> 6, e = cc & 63;
        int b = row0 >> 11, s0 = row0 & 2047;
        if (sel < 2) {
          unsigned short* base = (unsigned short*)outp + (size_t)sel * 8388608;
#pragma unroll
          for (int r = 0; r < 4; r++) {
            // q scaled by log2e/sqrt(D_MODEL) so attn can use native exp2
            float v2 = (sel == 0) ? acc[mi][ni][r] * 0.04508422f : acc[mi][ni][r];
            base[((size_t)((b * N_HEADS + h) * SEQ + (s0 + r))) * HEAD + e] = f2b(v2);
          }
        } else {
          unsigned short* base = (unsigned short*)outp + (size_t)2 * 8388608;
          short4v pk;
#pragma unroll
          for (int r = 0; r < 4; r++) pk[r] = (short)f2b(acc[mi][ni][r]);
          *(short4v*)(base + ((size_t)((b * N_HEADS + h) * HEAD + e)) * SEQ + s0) = pk;
        }
      } else {  // epi 2: relu -> bf16
#pragma unroll
        for (int r = 0; r < 4; r++)
          ((unsigned short*)outp)[(size_t)(row0 + r) * N + col] =
              f2b(fmaxf(acc[mi][ni][r] + biasf[col], 0.0f));
      }
    }
  }
}

// ---------------- 256x128x64 bf16 GEMM, 8-wave 2-phase counted-vmcnt pipeline ------
// For the N=1024 GEMMs (Wo, W2): grid 32x8 = 256 blocks = 1/CU, 512 thr = 8 waves
// (4M x 2N, 64x64 per wave). LDS 96 KiB: A 2x[256][64], B 2x[128][64], chunk-XOR
// swizzled (content at (r,cc) = logical chunk cc^(r&7), staged via pre-swizzled src).
// 2 phases/K-tile, 16 MFMA each; counted vmcnt(4) once per tile.
// epi 1: fp32 out = acc + biasf[col] + residf[row*N+col]
// epi 3: fp32 out = acc + biasf[col] + b2f(residb[row*N+col])
__global__ __launch_bounds__(512, 2) void gemm256n(
    const unsigned short* __restrict__ A, const unsigned short* __restrict__ BT,
    const float* __restrict__ biasf, const float* __restrict__ residf,
    const unsigned short* __restrict__ residb, void* __restrict__ outp,
    int M, int N, int K, int epi)
{
  __shared__ unsigned short a_sh[2 * 256 * 64];   // 64 KiB
  __shared__ unsigned short b_sh[2 * 128 * 64];   // 32 KiB

  const int tid  = threadIdx.x;
  const int lane = tid & 63;
  const int wave = tid >> 6;        // 0..7
  const int quad = lane >> 4;
  const int l15  = lane & 15;
  const int wm   = wave >> 1;       // 0..3
  const int wn   = wave & 1;        // 0..1

  // XCD swizzle: 32 row-tiles, 4 per XCD; 8 col-tiles
  const int lin = blockIdx.y * gridDim.x + blockIdx.x;
  const int xcd = lin & 7, j = lin >> 3;
  const int m0 = (xcd * 4 + (j & 3)) * 256;
  const int n0 = (j >> 2) * 128;

  const int u  = tid >> 3;                       // 0..63
  const int sc = (tid & 7) ^ (u & 7);
  const unsigned short* a_src = A  + (size_t)(m0 + u) * K + sc * 8;
  const unsigned short* b_src = BT + (size_t)(n0 + u) * K + sc * 8;
  unsigned short* a_dst = a_sh + wave * 512;
  unsigned short* b_dst = b_sh + wave * 512;

#define SA(T, Rc) load16_lds(a_src + (size_t)(Rc) * K + (T) * 64, \
                             a_dst + ((T) & 1) * 16384 + (Rc) * 64)
#define SB(T, Rb) load16_lds(b_src + (size_t)(Rb) * K + (T) * 64, \
                             b_dst + ((T) & 1) * 8192 + (Rb) * 64)
#define STG_A0(T) do { SA(T, 0);   SA(T, 64);  } while (0)   // rows 0..127
#define STG_A1(T) do { SA(T, 128); SA(T, 192); } while (0)   // rows 128..255
#define STG_B(T)  do { SB(T, 0);   SB(T, 64);  } while (0)   // all 128 B rows

  floatx4 acc[4][4] = {};
  short8 aF[2][2];        // current QM: [mi][kh]
  short8 bF[2][2][2];     // [QN][ni][kh] - held across the tile
  const unsigned short* ash = a_sh;
  const unsigned short* bsh = b_sh;

#define LDA(QM) \
  _Pragma("unroll") for (int mi = 0; mi < 2; mi++) \
  _Pragma("unroll") for (int kh = 0; kh < 2; kh++) \
    aF[mi][kh] = *(const short8*)(ash + ((QM) * 128 + wm * 32 + mi * 16 + l15) * 64 \
                                  + (((kh * 4 + quad) ^ (l15 & 7)) * 8));
#define LDB(QN) \
  _Pragma("unroll") for (int ni = 0; ni < 2; ni++) \
  _Pragma("unroll") for (int kh = 0; kh < 2; kh++) \
    bF[QN][ni][kh] = *(const short8*)(bsh + ((QN) * 64 + wn * 32 + ni * 16 + l15) * 64 \
                                      + (((kh * 4 + quad) ^ (l15 & 7)) * 8));
#define MM2(QM) \
  _Pragma("unroll") for (int qn = 0; qn < 2; qn++) \
  _Pragma("unroll") for (int mi = 0; mi < 2; mi++) \
  _Pragma("unroll") for (int ni = 0; ni < 2; ni++) { \
    acc[(QM) * 2 + mi][qn * 2 + ni] = \
        mfma16(aF[mi][0], bF[qn][ni][0], acc[(QM) * 2 + mi][qn * 2 + ni]); \
    acc[(QM) * 2 + mi][qn * 2 + ni] = \
        mfma16(aF[mi][1], bF[qn][ni][1], acc[(QM) * 2 + mi][qn * 2 + ni]); \
  }
#define PH_VM(N) asm volatile("s_waitcnt vmcnt(" #N ")" ::: "memory");
#define PH_MID() \
  __builtin_amdgcn_s_barrier(); \
  asm volatile("s_waitcnt lgkmcnt(0)" ::: "memory"); \
  __builtin_amdgcn_sched_barrier(0); \
  __builtin_amdgcn_s_setprio(1);
#define PH_END() \
  __builtin_amdgcn_s_setprio(0); \
  __builtin_amdgcn_s_barrier();

  const int NT = K >> 6;

  // prologue: tile0 fully + tile1 ph1-needed regions
  STG_A0(0); STG_B(0); STG_A1(0); STG_A0(1); STG_B(1);
  PH_VM(4)                            // retire all 6 of tile 0; keep A0(1),B(1)
  __builtin_amdgcn_s_barrier();

  for (int t = 0; t < NT - 2; ++t) {
    ash = a_sh + (t & 1) * 16384;
    bsh = b_sh + (t & 1) * 8192;

    LDA(0) LDB(0) LDB(1)
    STG_A1(t + 1);
    PH_MID() MM2(0) PH_END();

    LDA(1)
    STG_A0(t + 2); STG_B(t + 2);
    PH_VM(4)
    PH_MID() MM2(1) PH_END();
  }
  {// tile NT-2: stage only A1(NT-1); drain
    const int t = NT - 2;
    ash = a_sh + (t & 1) * 16384;
    bsh = b_sh + (t & 1) * 8192;

    LDA(0) LDB(0) LDB(1)
    STG_A1(t + 1);
    PH_MID() MM2(0) PH_END();

    LDA(1)
    PH_VM(0)
    PH_MID() MM2(1) PH_END();
  }
  {// tile NT-1: no staging
    const int t = NT - 1;
    ash = a_sh + (t & 1) * 16384;
    bsh = b_sh + (t & 1) * 8192;

    LDA(0) LDB(0) LDB(1)
    PH_MID() MM2(0) PH_END();

    LDA(1)
    PH_MID() MM2(1) PH_END();
  }

#undef SA
#undef SB
#undef STG_A0
#undef STG_A1
#undef STG_B
#undef LDA
#undef LDB
#undef MM2
#undef PH_VM
#undef PH_MID
#undef PH_END

#pragma unroll
  for (int am = 0; am < 4; am++) {
    const int row0 = m0 + (am >> 1) * 128 + wm * 32 + (am & 1) * 16 + quad * 4;
#pragma unroll
    for (int bn = 0; bn < 4; bn++) {
      const int col = n0 + (bn >> 1) * 64 + wn * 32 + (bn & 1) * 16 + l15;
      if (epi == 1) {
#pragma unroll
        for (int r = 0; r < 4; r++)
          ((float*)outp)[(size_t)(row0 + r) * N + col] =
              acc[am][bn][r] + biasf[col] + residf[(size_t)(row0 + r) * N + col];
      } else {
#pragma unroll
        for (int r = 0; r < 4; r++)
          ((float*)outp)[(size_t)(row0 + r) * N + col] =
              acc[am][bn][r] + biasf[col] + b2f(residb[(size_t)(row0 + r) * N + col]);
      }
    }
  }
}

// ---------------- flash attention v3: S^T formulation, exp2 + MFMA row-sum ----------
// REVERTED to the Round-4 verified version (87.4 us, MfmaUtil 37.5%): single-buffer
// K/V LDS staging via coalesced global_load_lds + chunk-swizzled ds_reads.
// Two failed lines are now closed with counter evidence:
//  - R5 K/V double-buffer: cost a resident block, latency-bound kernel lost TLP (-44%)
//  - R6-R8 no-staging: fragment gathers are NOT wave-coalesced -> ~16 cache-line
//    transactions per load inst; TA-bound at 13% MfmaUtil despite zero barriers.
// Lesson: fragment-layout gathers must go through LDS; only staging loads coalesce.
__global__ __launch_bounds__(256, 4) void attn_kernel(
    const unsigned short* __restrict__ q, const unsigned short* __restrict__ k,
    const unsigned short* __restrict__ vt, unsigned short* __restrict__ o)
{
  const int bh = blockIdx.y;          // 0..63
  const int qt = blockIdx.x;          // 0..15
  const int tid = threadIdx.x, lane = tid & 63, wave = tid >> 6;
  const int quad = lane >> 4, l15 = lane & 15;
  const size_t base = (size_t)bh * SEQ * HEAD;

  __shared__ unsigned short k_sh[64 * 64];   // [t][e], chunk-swizzled
  __shared__ unsigned short vT_sh[64 * 64];  // [e][t], chunk-swizzled
  __shared__ unsigned short p_sh[4 * 32 * 72];
  unsigned short* pw = p_sh + wave * 32 * 72;  // wave-private P [m 32][t 64+pad]

  short8 qf[2][2];
#pragma unroll
  for (int mj = 0; mj < 2; mj++) {
    const unsigned short* qp =
        q + base + (size_t)(qt * 128 + wave * 32 + mj * 16 + l15) * HEAD;
    qf[mj][0] = *(const short8*)(qp + quad * 8);
    qf[mj][1] = *(const short8*)(qp + 32 + quad * 8);
  }

  floatx4 oacc[2][4] = {};
  floatx4 rsacc[2] = {};   // row sums live in col 0 (lanes with l15==0)

  // ones B-fragment: B[row 0][k] = 1.0bf16, rows 1..15 = 0
  short8 onesf;
  {
    short ov = (l15 == 0) ? (short)0x3F80 : (short)0;
#pragma unroll
    for (int jj = 0; jj < 8; jj++) onesf[jj] = ov;
  }

  const int r8 = lane >> 3, slot = lane & 7;

  for (int kt = 0; kt < SEQ / 64; kt++) {
    __syncthreads();
#pragma unroll
    for (int i = 0; i < 2; i++) {
      int t = wave * 16 + i * 8 + r8;
      int cg = slot ^ (t & 7);
      load16_lds(k + base + (size_t)(kt * 64 + t) * HEAD + cg * 8,
                 k_sh + (wave * 16 + i * 8) * 64);
      load16_lds(vt + base + (size_t)t * SEQ + kt * 64 + cg * 8,
                 vT_sh + (wave * 16 + i * 8) * 64);
    }
    __syncthreads();

    // S^T tile: A = K rows (t), B = Q rows (m); D rows=t, cols=m
#pragma unroll
    for (int ti = 0; ti < 4; ti++) {
      int t = ti * 16 + l15;
      short8 kf0 = *(const short8*)(k_sh + t * 64 + ((quad ^ (t & 7)) * 8));
      short8 kf1 = *(const short8*)(k_sh + t * 64 + (((4 + quad) ^ (t & 7)) * 8));
      floatx4 s0 = {0.f, 0.f, 0.f, 0.f}, s1 = {0.f, 0.f, 0.f, 0.f};
      __builtin_amdgcn_s_setprio(1);
      s0 = mfma16(kf0, qf[0][0], s0);
      s0 = mfma16(kf1, qf[0][1], s0);
      s1 = mfma16(kf0, qf[1][0], s1);
      s1 = mfma16(kf1, qf[1][1], s1);
      __builtin_amdgcn_s_setprio(0);
#pragma unroll
      for (int mj = 0; mj < 2; mj++) {
        floatx4 s = mj ? s1 : s0;
        float p0 = __builtin_amdgcn_exp2f(s[0]);
        float p1 = __builtin_amdgcn_exp2f(s[1]);
        float p2 = __builtin_amdgcn_exp2f(s[2]);
        float p3 = __builtin_amdgcn_exp2f(s[3]);
        uint2 u;
        u.x = __builtin_amdgcn_perm(__float_as_uint(p1), __float_as_uint(p0), 0x07060302u);
        u.y = __builtin_amdgcn_perm(__float_as_uint(p3), __float_as_uint(p2), 0x07060302u);
        *(uint2*)(pw + (mj * 16 + l15) * 72 + ti * 16 + quad * 4) = u;
      }
    }

    // O += P @ V   (A = P[m][t], B = V^T[e][t]); rs += P @ 1 on the MFMA pipe
    {
      short8 pf[2][2];
#pragma unroll
      for (int mj = 0; mj < 2; mj++) {
        pf[mj][0] = *(const short8*)(pw + (mj * 16 + l15) * 72 + quad * 8);
        pf[mj][1] = *(const short8*)(pw + (mj * 16 + l15) * 72 + 32 + quad * 8);
      }
      __builtin_amdgcn_s_setprio(1);
#pragma unroll
      for (int ni = 0; ni < 4; ni++) {
        int e = ni * 16 + l15;
        short8 bv0 = *(const short8*)(vT_sh + e * 64 + ((quad ^ (e & 7)) * 8));
        short8 bv1 = *(const short8*)(vT_sh + e * 64 + (((4 + quad) ^ (e & 7)) * 8));
#pragma unroll
        for (int mj = 0; mj < 2; mj++) {
          oacc[mj][ni] = mfma16(pf[mj][0], bv0, oacc[mj][ni]);
          oacc[mj][ni] = mfma16(pf[mj][1], bv1, oacc[mj][ni]);
        }
      }
#pragma unroll
      for (int mj = 0; mj < 2; mj++) {
        rsacc[mj] = mfma16(pf[mj][0], onesf, rsacc[mj]);
        rsacc[mj] = mfma16(pf[mj][1], onesf, rsacc[mj]);
      }
      __builtin_amdgcn_s_setprio(0);
    }
  }

  const int b = bh >> 4, h = bh & 15;
#pragma unroll
  for (int mj = 0; mj < 2; mj++)
#pragma unroll
    for (int r = 0; r < 4; r++) {
      int s = qt * 128 + wave * 32 + mj * 16 + quad * 4 + r;
      // rs for row m=quad*4+r sits in lane quad*16 (l15==0), element r
      float rsv = __shfl(rsacc[mj][r], quad * 16, 64);
      float inv = 1.0f / rsv;
#pragma unroll
      for (int ni = 0; ni < 4; ni++)
        o[((size_t)(b * SEQ + s)) * D_MODEL + h * HEAD + ni * 16 + l15] =
            f2b(oacc[mj][ni][r] * inv);
    }
}

// ---------------- layernorm: wave-per-row, no LDS/barrier ----------------
__global__ __launch_bounds__(256) void ln_kernel(
    const float* __restrict__ in, const float* __restrict__ g,
    const float* __restrict__ be, void* __restrict__ outp, int write_bf16)
{
  const int row = blockIdx.x * 4 + (threadIdx.x >> 6);
  const int lane = threadIdx.x & 63;
  const float* xp = in + (size_t)row * D_MODEL;
  float4 xv[4];
  float s = 0.0f, ss = 0.0f;
#pragma unroll
  for (int j = 0; j < 4; j++) {
    xv[j] = *(const float4*)(xp + j * 256 + lane * 4);
    s += (xv[j].x + xv[j].y) + (xv[j].z + xv[j].w);
    ss += (xv[j].x * xv[j].x + xv[j].y * xv[j].y) +
          (xv[j].z * xv[j].z + xv[j].w * xv[j].w);
  }
#pragma unroll
  for (int m = 1; m < 64; m <<= 1) {
    s += __shfl_xor(s, m, 64);
    ss += __shfl_xor(ss, m, 64);
  }
  float mean = s * (1.0f / 1024.0f);
  float var = fmaxf((ss - 1024.0f * mean * mean) * (1.0f / 1023.0f), 0.0f);
  float inv = 1.0f / (sqrtf(var) + 1e-6f);
#pragma unroll
  for (int j = 0; j < 4; j++) {
    int c = j * 256 + lane * 4;
    float4 g4 = *(const float4*)(g + c);
    float4 b4 = *(const float4*)(be + c);
    float y0 = g4.x * ((xv[j].x + mean) * inv) + b4.x;
    float y1 = g4.y * ((xv[j].y + mean) * inv) + b4.y;
    float y2 = g4.z * ((xv[j].z + mean) * inv) + b4.z;
    float y3 = g4.w * ((xv[j].w + mean) * inv) + b4.w;
    if (write_bf16) {
      short4v o4;
      o4[0] = (short)f2b(y0); o4[1] = (short)f2b(y1);
      o4[2] = (short)f2b(y2); o4[3] = (short)f2b(y3);
      *(short4v*)((unsigned short*)outp + (size_t)row * D_MODEL + c) = o4;
    } else {
      float4 o4 = {y0, y1, y2, y3};
      *(float4*)((float*)outp + (size_t)row * D_MODEL + c) = o4;
    }
  }
}

extern "C" void kernel_launch(void* const* d_in, const int* in_sizes, int n_in,
                              void* d_out, int out_size, void* d_ws, size_t ws_size,
                              hipStream_t stream)
{
  const float* x   = (const float*)d_in[0];
  const float* Wq  = (const float*)d_in[1];
  const float* Wk  = (const float*)d_in[2];
  const float* Wv  = (const float*)d_in[3];
  const float* Wo  = (const float*)d_in[4];
  const float* bo  = (const float*)d_in[5];
  const float* W1  = (const float*)d_in[6];
  const float* b1  = (const float*)d_in[7];
  const float* W2  = (const float*)d_in[8];
  const float* b2  = (const float*)d_in[9];
  const float* g1  = (const float*)d_in[10];
  const float* be1 = (const float*)d_in[11];
  const float* g2  = (const float*)d_in[12];
  const float* be2 = (const float*)d_in[13];
  float* out = (float*)d_out;

  // ws layout (bf16-element offsets; total 104 MiB). vws is V^T [bh][e][s].
  unsigned short* ws     = (unsigned short*)d_ws;
  unsigned short* w1_bt  = ws;
  unsigned short* w2_bt  = ws + 4194304;
  unsigned short* qkv_bt = ws + 8388608;
  unsigned short* wo_bt  = ws + 11534336;
  unsigned short* x_bf   = ws + 12582912;
  unsigned short* qws    = ws + 20971520;
  unsigned short* kws    = ws + 29360128;
  unsigned short* vws    = ws + 37748736;
  unsigned short* ows    = x_bf;                    // overlay x_bf (dead after QKV gemm)
  float*          r1     = (float*)(ws + 20971520); // overlay q+k (dead after attn)
  unsigned short* h1_bf  = x_bf;                    // overlay o (dead after Wo gemm)
  unsigned short* ff1    = ws + 20971520;           // overlay r1+v^T+fresh, 64 MiB

  dim3 blk(256);

  prep_kernel<<<11264, blk, 0, stream>>>(x, x_bf, Wq, Wk, Wv, qkv_bt,
                                         Wo, wo_bt, W1, w1_bt, W2, w2_bt);

  // q,k,v = x @ [Wq|Wk|Wv]  (q scaled log2e/32; v written transposed) -- 256^2 pipeline
  gemm256<<<dim3(3072 / 256, TOKENS / 256), dim3(512), 0, stream>>>(
      x_bf, qkv_bt, nullptr, qws, TOKENS, 3072, 1024, 0);
  // o = attention(q,k,v)
  attn_kernel<<<dim3(SEQ / 128, BATCH * N_HEADS), blk, 0, stream>>>(qws, kws, vws, ows);
  // r1 = x + (o @ Wo + bo)   (fp32)  -- 256x128 pipeline, 256 blocks
  gemm256n<<<dim3(1024 / 128, TOKENS / 256), dim3(512), 0, stream>>>(
      ows, wo_bt, bo, x, nullptr, r1, TOKENS, 1024, 1024, 1);
  // h1 = LN(r1) -> bf16
  ln_kernel<<<TOKENS / 4, blk, 0, stream>>>(r1, g1, be1, h1_bf, 1);
  // ff1 = relu(h1 @ W1 + b1) -> bf16  -- 256^2 pipeline
  gemm256<<<dim3(4096 / 256, TOKENS / 256), dim3(512), 0, stream>>>(
      h1_bf, w1_bt, b1, ff1, TOKENS, 4096, 1024, 2);
  // r2 = h1 + (ff1 @ W2 + b2) -> fp32 into d_out  -- 256x128 pipeline
  gemm256n<<<dim3(1024 / 128, TOKENS / 256), dim3(512), 0, stream>>>(
      ff1, w2_bt, b2, nullptr, h1_bf, out, TOKENS, 1024, 4096, 3);
  // out = LN(r2), in-place fp32
  ln_kernel<<<TOKENS / 4, blk, 0, stream>>>(out, g2, be2, out, 0);
}

// Round 10
// 467.477 us; speedup vs baseline: 1.5172x; 1.0031x over previous
//
#include <hip/hip_runtime.h>

typedef short short8 __attribute__((ext_vector_type(8)));
typedef short short4v __attribute__((ext_vector_type(4)));
typedef float floatx4 __attribute__((ext_vector_type(4)));

#define D_MODEL 1024
#define N_HEADS 16
#define HEAD    64
#define D_FF    4096
#define SEQ     2048
#define BATCH   4
#define TOKENS  (BATCH*SEQ)   // 8192

__device__ __forceinline__ float b2f(unsigned short u) {
  return __uint_as_float(((unsigned)u) << 16);
}
__device__ __forceinline__ unsigned short f2b(float f) {
  unsigned u = __float_as_uint(f);
  unsigned r = 0x7fffu + ((u >> 16) & 1u);
  return (unsigned short)((u + r) >> 16);
}
__device__ __forceinline__ floatx4 mfma16(short8 a, short8 b, floatx4 c) {
  return __builtin_amdgcn_mfma_f32_16x16x32_bf16(a, b, c, 0, 0, 0);
}
__device__ __forceinline__ void load16_lds(const unsigned short* g, unsigned short* l) {
  __builtin_amdgcn_global_load_lds((const __attribute__((address_space(1))) void*)g,
                                   (__attribute__((address_space(3))) void*)l, 16, 0, 0);
}

// ---------------- fused prep: x->bf16, QKV repack, Wo/W1/W2 transpose ----------------
__device__ __forceinline__ void transp_body(
    const float* __restrict__ src, unsigned short* __restrict__ dst,
    int R, int C, int bx, int by, float (*t)[65])
{
  int cb = bx * 64, rb = by * 64;
#pragma unroll
  for (int i = 0; i < 16; i++) {
    int idx = i * 256 + threadIdx.x;
    int lr = idx >> 6, lc = idx & 63;
    t[lr][lc] = src[(size_t)(rb + lr) * C + cb + lc];
  }
  __syncthreads();
#pragma unroll
  for (int i = 0; i < 16; i++) {
    int idx = i * 256 + threadIdx.x;
    int lc = idx >> 6, lr = idx & 63;
    dst[(size_t)(cb + lc) * R + rb + lr] = f2b(t[lr][lc]);
  }
}

__global__ __launch_bounds__(256) void prep_kernel(
    const float* __restrict__ x, unsigned short* __restrict__ x_bf,
    const float* __restrict__ Wq, const float* __restrict__ Wk,
    const float* __restrict__ Wv, unsigned short* __restrict__ qkv_bt,
    const float* __restrict__ Wo, unsigned short* __restrict__ wo_bt,
    const float* __restrict__ W1, unsigned short* __restrict__ w1_bt,
    const float* __restrict__ W2, unsigned short* __restrict__ w2_bt)
{
  __shared__ float t[64][65];
  int bid = blockIdx.x;
  if (bid < 8192) {                       // x fp32 -> bf16
    int idx = bid * 1024 + threadIdx.x * 4;
    float4 v = *(const float4*)(x + idx);
    short4v o;
    o[0] = (short)f2b(v.x); o[1] = (short)f2b(v.y);
    o[2] = (short)f2b(v.z); o[3] = (short)f2b(v.w);
    *(short4v*)(x_bf + idx) = o;
  } else if (bid < 8960) {                // QKV repack: W[h][d][e] -> [c][d]
    int by = bid - 8192;
    int xt = by & 15, z = by >> 4;
    int sel = z >> 4, h = z & 15;
    const float* W = (sel == 0) ? Wq : ((sel == 1) ? Wk : Wv);
    const float* src = W + (size_t)h * D_MODEL * HEAD;
    int rb = xt * 64;
#pragma unroll
    for (int i = 0; i < 16; i++) {
      int idx = i * 256 + threadIdx.x;
      int lr = idx >> 6, lc = idx & 63;
      t[lr][lc] = src[(size_t)(rb + lr) * HEAD + lc];
    }
    __syncthreads();
    unsigned short* d0 = qkv_bt + (size_t)(sel * 1024 + h * 64) * D_MODEL;
#pragma unroll
    for (int i = 0; i < 16; i++) {
      int idx = i * 256 + threadIdx.x;
      int lc = idx >> 6, lr = idx & 63;
      d0[(size_t)lc * D_MODEL + rb + lr] = f2b(t[lr][lc]);
    }
  } else if (bid < 9216) {                // Wo^T
    int i = bid - 8960;
    transp_body(Wo, wo_bt, 1024, 1024, i & 15, i >> 4, t);
  } else if (bid < 10240) {               // W1^T
    int i = bid - 9216;
    transp_body(W1, w1_bt, 1024, 4096, i & 63, i >> 6, t);
  } else {                                // W2^T
    int i = bid - 10240;
    transp_body(W2, w2_bt, 4096, 1024, i & 15, i >> 4, t);
  }
}

// ---------------- 256x256x64 bf16 GEMM, 8-wave 4-phase counted-vmcnt pipeline ------
// Single vmcnt(4) per K-tile at phase 4. Ledger: at tile t ph4, outstanding =
// A1(t+1),B1(t+1),A0(t+2),B0(t+2) = 8 loads; vmcnt(4) retires A1(t+1),B1(t+1)
// and everything older -> all of tile t+1 landed before tile t+1 ph1 reads it.
// WAR: STG into a region is issued >=1 full phase after that region's readers
// drained (lgkmcnt(0) before the MFMA of the reading phase).
// epi 0 = QKV split write (q pre-scaled by log2e/32 for exp2 softmax), epi 2 = relu bf16.
__global__ __launch_bounds__(512, 2) void gemm256(
    const unsigned short* __restrict__ A, const unsigned short* __restrict__ BT,
    const float* __restrict__ biasf, void* __restrict__ outp,
    int M, int N, int K, int epi)
{
  __shared__ unsigned short a_sh[2 * 256 * 64];   // [buf][row][64]
  __shared__ unsigned short b_sh[2 * 256 * 64];   // [buf][permrow][64]

  const int tid  = threadIdx.x;
  const int lane = tid & 63;
  const int wave = tid >> 6;        // 0..7
  const int quad = lane >> 4;
  const int l15  = lane & 15;
  const int wm   = wave >> 2;       // 0..1
  const int wn   = wave & 3;        // 0..3

  // XCD swizzle: M/256 = 32 row-tiles, 4 per XCD (contiguous A band per XCD L2)
  const int lin = blockIdx.y * gridDim.x + blockIdx.x;
  const int xcd = lin & 7, j = lin >> 3;
  const int m0 = (xcd * 4 + (j & 3)) * 256;
  const int n0 = (j >> 2) * 256;

  // staging: thread covers (row u, chunk tid&7) of each 64-row call;
  // source chunk pre-swizzled so LDS content at (r,cc) = logical chunk cc^(r&7)
  const int u  = tid >> 3;                       // 0..63
  const int sc = (tid & 7) ^ (u & 7);
  const unsigned short* a_src = A  + (size_t)(m0 + u) * K + sc * 8;
  const int borig = ((u >> 5) * 64) + (u & 31);  // perm-row -> orig BT row (base)
  const unsigned short* b_src = BT + (size_t)(n0 + borig) * K + sc * 8;
  unsigned short* a_dst = a_sh + wave * 512;     // + buf*16384 + Rc*64
  unsigned short* b_dst = b_sh + wave * 512;

#define SA(T, Rc)  load16_lds(a_src + (size_t)(Rc) * K + (T) * 64, \
                              a_dst + ((T) & 1) * 16384 + (Rc) * 64)
#define SB(T, Rb, Radd) load16_lds(b_src + (size_t)(Radd) * K + (T) * 64, \
                              b_dst + ((T) & 1) * 16384 + (Rb) * 64)
#define STG_A0(T) do { SA(T, 0);   SA(T, 128); } while (0)          // qm=0 rows
#define STG_A1(T) do { SA(T, 64);  SA(T, 192); } while (0)          // qm=1 rows
#define STG_B0(T) do { SB(T, 0, 0);    SB(T, 64, 128); } while (0)  // qn=0 rows
#define STG_B1(T) do { SB(T, 128, 32); SB(T, 192, 160); } while (0) // qn=1 rows

  floatx4 acc[8][4] = {};
  short8 aF[4][2];        // current qm sub-band, both k-halves
  short8 bF[2][2][2];     // [qn][ni][kh] - both qn sets held across the tile
  const unsigned short* ash = a_sh;
  const unsigned short* bsh = b_sh;

#define LDA(QM) \
  _Pragma("unroll") for (int mi = 0; mi < 4; mi++) \
  _Pragma("unroll") for (int kh = 0; kh < 2; kh++) \
    aF[mi][kh] = *(const short8*)(ash + (wm * 128 + (QM) * 64 + mi * 16 + l15) * 64 \
                                  + (((kh * 4 + quad) ^ (l15 & 7)) * 8));
#define LDB(QN) \
  _Pragma("unroll") for (int ni = 0; ni < 2; ni++) \
  _Pragma("unroll") for (int kh = 0; kh < 2; kh++) \
    bF[QN][ni][kh] = *(const short8*)(bsh + ((QN) * 128 + wn * 32 + ni * 16 + l15) * 64 \
                                      + (((kh * 4 + quad) ^ (l15 & 7)) * 8));
#define MM(QM, QN) \
  _Pragma("unroll") for (int mi = 0; mi < 4; mi++) \
  _Pragma("unroll") for (int ni = 0; ni < 2; ni++) { \
    acc[(QM) * 4 + mi][(QN) * 2 + ni] = \
        mfma16(aF[mi][0], bF[QN][ni][0], acc[(QM) * 4 + mi][(QN) * 2 + ni]); \
    acc[(QM) * 4 + mi][(QN) * 2 + ni] = \
        mfma16(aF[mi][1], bF[QN][ni][1], acc[(QM) * 4 + mi][(QN) * 2 + ni]); \
  }
#define PH_VM(N) asm volatile("s_waitcnt vmcnt(" #N ")" ::: "memory");
#define PH_MID() \
  __builtin_amdgcn_s_barrier(); \
  asm volatile("s_waitcnt lgkmcnt(0)" ::: "memory"); \
  __builtin_amdgcn_sched_barrier(0); \
  __builtin_amdgcn_s_setprio(1);
#define PH_END() \
  __builtin_amdgcn_s_setprio(0); \
  __builtin_amdgcn_s_barrier();

  const int NT = K >> 6;

  // prologue: tile0 fully + tile1 first-needed halves
  STG_A0(0); STG_B0(0); STG_A1(0); STG_B1(0); STG_A0(1); STG_B0(1);
  PH_VM(4)                                           // retire all of tile 0
  __builtin_amdgcn_s_barrier();

  for (int t = 0; t < NT - 2; ++t) {
    ash = a_sh + (t & 1) * 16384;
    bsh = b_sh + (t & 1) * 16384;

    LDA(0) LDB(0)
    STG_A1(t + 1);
    PH_MID() MM(0, 0) PH_END();

    LDB(1)
    STG_B1(t + 1);
    PH_MID() MM(0, 1) PH_END();

    LDA(1)
    STG_A0(t + 2);
    PH_MID() MM(1, 0) PH_END();

    STG_B0(t + 2);
    PH_VM(4)
    PH_MID() MM(1, 1) PH_END();
  }
  {// tile NT-2: no t+2 staging; drain toward tail
    const int t = NT - 2;
    ash = a_sh + (t & 1) * 16384;
    bsh = b_sh + (t & 1) * 16384;

    LDA(0) LDB(0)
    STG_A1(t + 1);
    PH_MID() MM(0, 0) PH_END();

    LDB(1)
    STG_B1(t + 1);
    PH_MID() MM(0, 1) PH_END();

    LDA(1)
    PH_MID() MM(1, 0) PH_END();

    PH_VM(0)
    PH_MID() MM(1, 1) PH_END();
  }
  {// tile NT-1: final tile, no staging, no waits needed
    const int t = NT - 1;
    ash = a_sh + (t & 1) * 16384;
    bsh = b_sh + (t & 1) * 16384;

    LDA(0) LDB(0)
    PH_MID() MM(0, 0) PH_END();

    LDB(1)
    PH_MID() MM(0, 1) PH_END();

    LDA(1)
    PH_MID() MM(1, 0) PH_END();

    PH_MID() MM(1, 1) PH_END();
  }

#undef SA
#undef SB
#undef STG_A0
#undef STG_A1
#undef STG_B0
#undef STG_B1
#undef LDA
#undef LDB
#undef MM
#undef PH_VM
#undef PH_MID
#undef PH_END

#pragma unroll
  for (int mi = 0; mi < 8; mi++) {
#pragma unroll
    for (int ni = 0; ni < 4; ni++) {
      const int col = n0 + wn * 64 + ni * 16 + l15;
      const int row0 = m0 + wm * 128 + mi * 16 + quad * 4;
      if (epi == 0) {
        int sel = col >> 10;
        int cc = col & 1023;
        int h = cc >> 6, e = cc & 63;
        int b = row0 >> 11, s0 = row0 & 2047;
        if (sel < 2) {
          unsigned short* base = (unsigned short*)outp + (size_t)sel * 8388608;
#pragma unroll
          for (int r = 0; r < 4; r++) {
            // q scaled by log2e/sqrt(D_MODEL) so attn can use native exp2
            float v2 = (sel == 0) ? acc[mi][ni][r] * 0.04508422f : acc[mi][ni][r];
            base[((size_t)((b * N_HEADS + h) * SEQ + (s0 + r))) * HEAD + e] = f2b(v2);
          }
        } else {
          unsigned short* base = (unsigned short*)outp + (size_t)2 * 8388608;
          short4v pk;
#pragma unroll
          for (int r = 0; r < 4; r++) pk[r] = (short)f2b(acc[mi][ni][r]);
          *(short4v*)(base + ((size_t)((b * N_HEADS + h) * HEAD + e)) * SEQ + s0) = pk;
        }
      } else {  // epi 2: relu -> bf16
#pragma unroll
        for (int r = 0; r < 4; r++)
          ((unsigned short*)outp)[(size_t)(row0 + r) * N + col] =
              f2b(fmaxf(acc[mi][ni][r] + biasf[col], 0.0f));
      }
    }
  }
}

// ---------------- 256x128x64 bf16 GEMM, 8-wave 2-phase counted-vmcnt pipeline ------
// For the N=1024 GEMMs (Wo, W2): grid 32x8 = 256 blocks = 1/CU, 512 thr = 8 waves
// (4M x 2N, 64x64 per wave). LDS 96 KiB: A 2x[256][64], B 2x[128][64], chunk-XOR
// swizzled (content at (r,cc) = logical chunk cc^(r&7), staged via pre-swizzled src).
// 2 phases/K-tile, 16 MFMA each; counted vmcnt(4) once per tile.
// epi 1: fp32 out = acc + biasf[col] + residf[row*N+col]
// epi 3: fp32 out = acc + biasf[col] + b2f(residb[row*N+col])
__global__ __launch_bounds__(512, 2) void gemm256n(
    const unsigned short* __restrict__ A, const unsigned short* __restrict__ BT,
    const float* __restrict__ biasf, const float* __restrict__ residf,
    const unsigned short* __restrict__ residb, void* __restrict__ outp,
    int M, int N, int K, int epi)
{
  __shared__ unsigned short a_sh[2 * 256 * 64];   // 64 KiB
  __shared__ unsigned short b_sh[2 * 128 * 64];   // 32 KiB

  const int tid  = threadIdx.x;
  const int lane = tid & 63;
  const int wave = tid >> 6;        // 0..7
  const int quad = lane >> 4;
  const int l15  = lane & 15;
  const int wm   = wave >> 1;       // 0..3
  const int wn   = wave & 1;        // 0..1

  // XCD swizzle: 32 row-tiles, 4 per XCD; 8 col-tiles
  const int lin = blockIdx.y * gridDim.x + blockIdx.x;
  const int xcd = lin & 7, j = lin >> 3;
  const int m0 = (xcd * 4 + (j & 3)) * 256;
  const int n0 = (j >> 2) * 128;

  const int u  = tid >> 3;                       // 0..63
  const int sc = (tid & 7) ^ (u & 7);
  const unsigned short* a_src = A  + (size_t)(m0 + u) * K + sc * 8;
  const unsigned short* b_src = BT + (size_t)(n0 + u) * K + sc * 8;
  unsigned short* a_dst = a_sh + wave * 512;
  unsigned short* b_dst = b_sh + wave * 512;

#define SA(T, Rc) load16_lds(a_src + (size_t)(Rc) * K + (T) * 64, \
                             a_dst + ((T) & 1) * 16384 + (Rc) * 64)
#define SB(T, Rb) load16_lds(b_src + (size_t)(Rb) * K + (T) * 64, \
                             b_dst + ((T) & 1) * 8192 + (Rb) * 64)
#define STG_A0(T) do { SA(T, 0);   SA(T, 64);  } while (0)   // rows 0..127
#define STG_A1(T) do { SA(T, 128); SA(T, 192); } while (0)   // rows 128..255
#define STG_B(T)  do { SB(T, 0);   SB(T, 64);  } while (0)   // all 128 B rows

  floatx4 acc[4][4] = {};
  short8 aF[2][2];        // current QM: [mi][kh]
  short8 bF[2][2][2];     // [QN][ni][kh] - held across the tile
  const unsigned short* ash = a_sh;
  const unsigned short* bsh = b_sh;

#define LDA(QM) \
  _Pragma("unroll") for (int mi = 0; mi < 2; mi++) \
  _Pragma("unroll") for (int kh = 0; kh < 2; kh++) \
    aF[mi][kh] = *(const short8*)(ash + ((QM) * 128 + wm * 32 + mi * 16 + l15) * 64 \
                                  + (((kh * 4 + quad) ^ (l15 & 7)) * 8));
#define LDB(QN) \
  _Pragma("unroll") for (int ni = 0; ni < 2; ni++) \
  _Pragma("unroll") for (int kh = 0; kh < 2; kh++) \
    bF[QN][ni][kh] = *(const short8*)(bsh + ((QN) * 64 + wn * 32 + ni * 16 + l15) * 64 \
                                      + (((kh * 4 + quad) ^ (l15 & 7)) * 8));
#define MM2(QM) \
  _Pragma("unroll") for (int qn = 0; qn < 2; qn++) \
  _Pragma("unroll") for (int mi = 0; mi < 2; mi++) \
  _Pragma("unroll") for (int ni = 0; ni < 2; ni++) { \
    acc[(QM) * 2 + mi][qn * 2 + ni] = \
        mfma16(aF[mi][0], bF[qn][ni][0], acc[(QM) * 2 + mi][qn * 2 + ni]); \
    acc[(QM) * 2 + mi][qn * 2 + ni] = \
        mfma16(aF[mi][1], bF[qn][ni][1], acc[(QM) * 2 + mi][qn * 2 + ni]); \
  }
#define PH_VM(N) asm volatile("s_waitcnt vmcnt(" #N ")" ::: "memory");
#define PH_MID() \
  __builtin_amdgcn_s_barrier(); \
  asm volatile("s_waitcnt lgkmcnt(0)" ::: "memory"); \
  __builtin_amdgcn_sched_barrier(0); \
  __builtin_amdgcn_s_setprio(1);
#define PH_END() \
  __builtin_amdgcn_s_setprio(0); \
  __builtin_amdgcn_s_barrier();

  const int NT = K >> 6;

  // prologue: tile0 fully + tile1 ph1-needed regions
  STG_A0(0); STG_B(0); STG_A1(0); STG_A0(1); STG_B(1);
  PH_VM(4)                            // retire all 6 of tile 0; keep A0(1),B(1)
  __builtin_amdgcn_s_barrier();

  for (int t = 0; t < NT - 2; ++t) {
    ash = a_sh + (t & 1) * 16384;
    bsh = b_sh + (t & 1) * 8192;

    LDA(0) LDB(0) LDB(1)
    STG_A1(t + 1);
    PH_MID() MM2(0) PH_END();

    LDA(1)
    STG_A0(t + 2); STG_B(t + 2);
    PH_VM(4)
    PH_MID() MM2(1) PH_END();
  }
  {// tile NT-2: stage only A1(NT-1); drain
    const int t = NT - 2;
    ash = a_sh + (t & 1) * 16384;
    bsh = b_sh + (t & 1) * 8192;

    LDA(0) LDB(0) LDB(1)
    STG_A1(t + 1);
    PH_MID() MM2(0) PH_END();

    LDA(1)
    PH_VM(0)
    PH_MID() MM2(1) PH_END();
  }
  {// tile NT-1: no staging
    const int t = NT - 1;
    ash = a_sh + (t & 1) * 16384;
    bsh = b_sh + (t & 1) * 8192;

    LDA(0) LDB(0) LDB(1)
    PH_MID() MM2(0) PH_END();

    LDA(1)
    PH_MID() MM2(1) PH_END();
  }

#undef SA
#undef SB
#undef STG_A0
#undef STG_A1
#undef STG_B
#undef LDA
#undef LDB
#undef MM2
#undef PH_VM
#undef PH_MID
#undef PH_END

#pragma unroll
  for (int am = 0; am < 4; am++) {
    const int row0 = m0 + (am >> 1) * 128 + wm * 32 + (am & 1) * 16 + quad * 4;
#pragma unroll
    for (int bn = 0; bn < 4; bn++) {
      const int col = n0 + (bn >> 1) * 64 + wn * 32 + (bn & 1) * 16 + l15;
      if (epi == 1) {
#pragma unroll
        for (int r = 0; r < 4; r++)
          ((float*)outp)[(size_t)(row0 + r) * N + col] =
              acc[am][bn][r] + biasf[col] + residf[(size_t)(row0 + r) * N + col];
      } else {
#pragma unroll
        for (int r = 0; r < 4; r++)
          ((float*)outp)[(size_t)(row0 + r) * N + col] =
              acc[am][bn][r] + biasf[col] + b2f(residb[(size_t)(row0 + r) * N + col]);
      }
    }
  }
}

// ---------------- flash attention v3: S^T formulation, exp2 + MFMA row-sum ----------
// R4-verified structure (staged K/V, 2 barriers/tile). This round: p_sh pad (+8
// shorts/row) replaced by a 16B-chunk XOR swizzle (chunk j' = j ^ (row&7)) --
// conflict-equivalent (reads 2-way: rows l15/l15+8 share banks; same as the old
// stride-72 layout) but saves 2 KiB: LDS 34816 -> 32768 = exactly 5 blocks/CU
// (was 4). +25% TLP on a latency-bound kernel (MfmaUtil 37.6 / VALUBusy 36.1,
// neither saturated). Worst case neutral: if a hidden LDS reservation keeps us
// at 4 blocks, behavior is identical to R9.
__global__ __launch_bounds__(256, 4) void attn_kernel(
    const unsigned short* __restrict__ q, const unsigned short* __restrict__ k,
    const unsigned short* __restrict__ vt, unsigned short* __restrict__ o)
{
  const int bh = blockIdx.y;          // 0..63
  const int qt = blockIdx.x;          // 0..15
  const int tid = threadIdx.x, lane = tid & 63, wave = tid >> 6;
  const int quad = lane >> 4, l15 = lane & 15;
  const size_t base = (size_t)bh * SEQ * HEAD;

  __shared__ unsigned short k_sh[64 * 64];   // [t][e], chunk-swizzled
  __shared__ unsigned short vT_sh[64 * 64];  // [e][t], chunk-swizzled
  __shared__ unsigned short p_sh[4 * 32 * 64];  // wave-private P, XOR chunk-swizzled
  unsigned short* pw = p_sh + wave * 2048;   // [m 32][t 64], chunk j^=(m&7)

  short8 qf[2][2];
#pragma unroll
  for (int mj = 0; mj < 2; mj++) {
    const unsigned short* qp =
        q + base + (size_t)(qt * 128 + wave * 32 + mj * 16 + l15) * HEAD;
    qf[mj][0] = *(const short8*)(qp + quad * 8);
    qf[mj][1] = *(const short8*)(qp + 32 + quad * 8);
  }

  floatx4 oacc[2][4] = {};
  floatx4 rsacc[2] = {};   // row sums live in col 0 (lanes with l15==0)

  // ones B-fragment: B[row 0][k] = 1.0bf16, rows 1..15 = 0
  short8 onesf;
  {
    short ov = (l15 == 0) ? (short)0x3F80 : (short)0;
#pragma unroll
    for (int jj = 0; jj < 8; jj++) onesf[jj] = ov;
  }

  const int r8 = lane >> 3, slot = lane & 7;

  for (int kt = 0; kt < SEQ / 64; kt++) {
    __syncthreads();
#pragma unroll
    for (int i = 0; i < 2; i++) {
      int t = wave * 16 + i * 8 + r8;
      int cg = slot ^ (t & 7);
      load16_lds(k + base + (size_t)(kt * 64 + t) * HEAD + cg * 8,
                 k_sh + (wave * 16 + i * 8) * 64);
      load16_lds(vt + base + (size_t)t * SEQ + kt * 64 + cg * 8,
                 vT_sh + (wave * 16 + i * 8) * 64);
    }
    __syncthreads();

    // S^T tile: A = K rows (t), B = Q rows (m); D rows=t, cols=m
#pragma unroll
    for (int ti = 0; ti < 4; ti++) {
      int t = ti * 16 + l15;
      short8 kf0 = *(const short8*)(k_sh + t * 64 + ((quad ^ (t & 7)) * 8));
      short8 kf1 = *(const short8*)(k_sh + t * 64 + (((4 + quad) ^ (t & 7)) * 8));
      floatx4 s0 = {0.f, 0.f, 0.f, 0.f}, s1 = {0.f, 0.f, 0.f, 0.f};
      __builtin_amdgcn_s_setprio(1);
      s0 = mfma16(kf0, qf[0][0], s0);
      s0 = mfma16(kf1, qf[0][1], s0);
      s1 = mfma16(kf0, qf[1][0], s1);
      s1 = mfma16(kf1, qf[1][1], s1);
      __builtin_amdgcn_s_setprio(0);
      // P write: uint2 (4 shorts) at row mj*16+l15, cols ti*16+quad*4;
      // 16B chunk j = ti*2 + (quad>>1), sub-half = quad&1, swizzle j ^= l15&7
      const int pco = (((ti * 2 + (quad >> 1)) ^ (l15 & 7)) << 3) + (quad & 1) * 4;
#pragma unroll
      for (int mj = 0; mj < 2; mj++) {
        floatx4 s = mj ? s1 : s0;
        float p0 = __builtin_amdgcn_exp2f(s[0]);
        float p1 = __builtin_amdgcn_exp2f(s[1]);
        float p2 = __builtin_amdgcn_exp2f(s[2]);
        float p3 = __builtin_amdgcn_exp2f(s[3]);
        uint2 u;
        u.x = __builtin_amdgcn_perm(__float_as_uint(p1), __float_as_uint(p0), 0x07060302u);
        u.y = __builtin_amdgcn_perm(__float_as_uint(p3), __float_as_uint(p2), 0x07060302u);
        *(uint2*)(pw + (mj * 16 + l15) * 64 + pco) = u;
      }
    }

    // O += P @ V   (A = P[m][t], B = V^T[e][t]); rs += P @ 1 on the MFMA pipe
    {
      short8 pf[2][2];
#pragma unroll
      for (int mj = 0; mj < 2; mj++) {
        // chunk quad (cols quad*8) and chunk 4+quad (cols 32+quad*8), XOR l15&7
        pf[mj][0] = *(const short8*)(pw + (mj * 16 + l15) * 64 +
                                     ((quad ^ (l15 & 7)) << 3));
        pf[mj][1] = *(const short8*)(pw + (mj * 16 + l15) * 64 +
                                     (((4 + quad) ^ (l15 & 7)) << 3));
      }
      __builtin_amdgcn_s_setprio(1);
#pragma unroll
      for (int ni = 0; ni < 4; ni++) {
        int e = ni * 16 + l15;
        short8 bv0 = *(const short8*)(vT_sh + e * 64 + ((quad ^ (e & 7)) * 8));
        short8 bv1 = *(const short8*)(vT_sh + e * 64 + (((4 + quad) ^ (e & 7)) * 8));
#pragma unroll
        for (int mj = 0; mj < 2; mj++) {
          oacc[mj][ni] = mfma16(pf[mj][0], bv0, oacc[mj][ni]);
          oacc[mj][ni] = mfma16(pf[mj][1], bv1, oacc[mj][ni]);
        }
      }
#pragma unroll
      for (int mj = 0; mj < 2; mj++) {
        rsacc[mj] = mfma16(pf[mj][0], onesf, rsacc[mj]);
        rsacc[mj] = mfma16(pf[mj][1], onesf, rsacc[mj]);
      }
      __builtin_amdgcn_s_setprio(0);
    }
  }

  const int b = bh >> 4, h = bh & 15;
#pragma unroll
  for (int mj = 0; mj < 2; mj++)
#pragma unroll
    for (int r = 0; r < 4; r++) {
      int s = qt * 128 + wave * 32 + mj * 16 + quad * 4 + r;
      // rs for row m=quad*4+r sits in lane quad*16 (l15==0), element r
      float rsv = __shfl(rsacc[mj][r], quad * 16, 64);
      float inv = 1.0f / rsv;
#pragma unroll
      for (int ni = 0; ni < 4; ni++)
        o[((size_t)(b * SEQ + s)) * D_MODEL + h * HEAD + ni * 16 + l15] =
            f2b(oacc[mj][ni][r] * inv);
    }
}

// ---------------- layernorm: wave-per-row, no LDS/barrier ----------------
__global__ __launch_bounds__(256) void ln_kernel(
    const float* __restrict__ in, const float* __restrict__ g,
    const float* __restrict__ be, void* __restrict__ outp, int write_bf16)
{
  const int row = blockIdx.x * 4 + (threadIdx.x >> 6);
  const int lane = threadIdx.x & 63;
  const float* xp = in + (size_t)row * D_MODEL;
  float4 xv[4];
  float s = 0.0f, ss = 0.0f;
#pragma unroll
  for (int j = 0; j < 4; j++) {
    xv[j] = *(const float4*)(xp + j * 256 + lane * 4);
    s += (xv[j].x + xv[j].y) + (xv[j].z + xv[j].w);
    ss += (xv[j].x * xv[j].x + xv[j].y * xv[j].y) +
          (xv[j].z * xv[j].z + xv[j].w * xv[j].w);
  }
#pragma unroll
  for (int m = 1; m < 64; m <<= 1) {
    s += __shfl_xor(s, m, 64);
    ss += __shfl_xor(ss, m, 64);
  }
  float mean = s * (1.0f / 1024.0f);
  float var = fmaxf((ss - 1024.0f * mean * mean) * (1.0f / 1023.0f), 0.0f);
  float inv = 1.0f / (sqrtf(var) + 1e-6f);
#pragma unroll
  for (int j = 0; j < 4; j++) {
    int c = j * 256 + lane * 4;
    float4 g4 = *(const float4*)(g + c);
    float4 b4 = *(const float4*)(be + c);
    float y0 = g4.x * ((xv[j].x + mean) * inv) + b4.x;
    float y1 = g4.y * ((xv[j].y + mean) * inv) + b4.y;
    float y2 = g4.z * ((xv[j].z + mean) * inv) + b4.z;
    float y3 = g4.w * ((xv[j].w + mean) * inv) + b4.w;
    if (write_bf16) {
      short4v o4;
      o4[0] = (short)f2b(y0); o4[1] = (short)f2b(y1);
      o4[2] = (short)f2b(y2); o4[3] = (short)f2b(y3);
      *(short4v*)((unsigned short*)outp + (size_t)row * D_MODEL + c) = o4;
    } else {
      float4 o4 = {y0, y1, y2, y3};
      *(float4*)((float*)outp + (size_t)row * D_MODEL + c) = o4;
    }
  }
}

extern "C" void kernel_launch(void* const* d_in, const int* in_sizes, int n_in,
                              void* d_out, int out_size, void* d_ws, size_t ws_size,
                              hipStream_t stream)
{
  const float* x   = (const float*)d_in[0];
  const float* Wq  = (const float*)d_in[1];
  const float* Wk  = (const float*)d_in[2];
  const float* Wv  = (const float*)d_in[3];
  const float* Wo  = (const float*)d_in[4];
  const float* bo  = (const float*)d_in[5];
  const float* W1  = (const float*)d_in[6];
  const float* b1  = (const float*)d_in[7];
  const float* W2  = (const float*)d_in[8];
  const float* b2  = (const float*)d_in[9];
  const float* g1  = (const float*)d_in[10];
  const float* be1 = (const float*)d_in[11];
  const float* g2  = (const float*)d_in[12];
  const float* be2 = (const float*)d_in[13];
  float* out = (float*)d_out;

  // ws layout (bf16-element offsets; total 104 MiB). vws is V^T [bh][e][s].
  unsigned short* ws     = (unsigned short*)d_ws;
  unsigned short* w1_bt  = ws;
  unsigned short* w2_bt  = ws + 4194304;
  unsigned short* qkv_bt = ws + 8388608;
  unsigned short* wo_bt  = ws + 11534336;
  unsigned short* x_bf   = ws + 12582912;
  unsigned short* qws    = ws + 20971520;
  unsigned short* kws    = ws + 29360128;
  unsigned short* vws    = ws + 37748736;
  unsigned short* ows    = x_bf;                    // overlay x_bf (dead after QKV gemm)
  float*          r1     = (float*)(ws + 20971520); // overlay q+k (dead after attn)
  unsigned short* h1_bf  = x_bf;                    // overlay o (dead after Wo gemm)
  unsigned short* ff1    = ws + 20971520;           // overlay r1+v^T+fresh, 64 MiB

  dim3 blk(256);

  prep_kernel<<<11264, blk, 0, stream>>>(x, x_bf, Wq, Wk, Wv, qkv_bt,
                                         Wo, wo_bt, W1, w1_bt, W2, w2_bt);

  // q,k,v = x @ [Wq|Wk|Wv]  (q scaled log2e/32; v written transposed) -- 256^2 pipeline
  gemm256<<<dim3(3072 / 256, TOKENS / 256), dim3(512), 0, stream>>>(
      x_bf, qkv_bt, nullptr, qws, TOKENS, 3072, 1024, 0);
  // o = attention(q,k,v)
  attn_kernel<<<dim3(SEQ / 128, BATCH * N_HEADS), blk, 0, stream>>>(qws, kws, vws, ows);
  // r1 = x + (o @ Wo + bo)   (fp32)  -- 256x128 pipeline, 256 blocks
  gemm256n<<<dim3(1024 / 128, TOKENS / 256), dim3(512), 0, stream>>>(
      ows, wo_bt, bo, x, nullptr, r1, TOKENS, 1024, 1024, 1);
  // h1 = LN(r1) -> bf16
  ln_kernel<<<TOKENS / 4, blk, 0, stream>>>(r1, g1, be1, h1_bf, 1);
  // ff1 = relu(h1 @ W1 + b1) -> bf16  -- 256^2 pipeline
  gemm256<<<dim3(4096 / 256, TOKENS / 256), dim3(512), 0, stream>>>(
      h1_bf, w1_bt, b1, ff1, TOKENS, 4096, 1024, 2);
  // r2 = h1 + (ff1 @ W2 + b2) -> fp32 into d_out  -- 256x128 pipeline
  gemm256n<<<dim3(1024 / 128, TOKENS / 256), dim3(512), 0, stream>>>(
      ff1, w2_bt, b2, nullptr, h1_bf, out, TOKENS, 1024, 4096, 3);
  // out = LN(r2), in-place fp32
  ln_kernel<<<TOKENS / 4, blk, 0, stream>>>(out, g2, be2, out, 0);
}